// Round 8
// baseline (2919.654 us; speedup 1.0000x reference)
//
#include <hip/hip_runtime.h>
#include <math.h>
#include <stdint.h>

#define Dd 32
#define TT 8192
#define NN 8191
#define KK 16
#define LOG2PI_ 1.8378770664093453

// ---------------- ws doubles ----------------
#define WSD_LOGC0  0
#define WSD_LOGZQ  1
#define WSD_MIXC   3
#define WSD_LDLAM  4
#define WSD_BTLAMB 5
#define WSD_PR     8
#define WSD_PT     1032
#define WSD_PM     2056
// ---------------- ws floats (base = byte 32768) ----------------
#define F_TAU      0
#define F_TAUMU    1024
#define F_LAM      1056
#define F_A        2080
#define F_B        3104
#define F_ATLAM    3136
#define F_ATLAMA   4160
#define F_LAMA     5184
#define F_LAMB     6208
#define F_ATLAMB   6240
#define F_SC       6272
#define F_LAMAK    6304
#define F_ATLAMAK  22688
#define F_LAMBK    39072
#define F_ATLAMBK  39584
#define F_BTLAMBK  40096
#define F_LOGDETK  40112
#define F_TPM      40128
#define F_J0       40160
#define F_H0       41184
#define F_MLAST    41216
#define F_COVT     41248
#define F_XT       42272
#define F_TPOW     42304
#define F_ALPHA    45632
#define F_BETA     176704
#define F_EZ       307776
#define F_SCAN     340544

// scan slot layout (stride 2148 floats)
#define SSTR   2148
#define POFF   0
#define QOFF   528
#define ROFF   1056
#define PPOFF  2080
#define QQOFF  2112
#define GAMOFF 2144
#define FLGOFF 2146
// affine leaf/composite layout
#define BG     0
#define BCZ    1024
#define BCM    1056
#define BP     1088

// out offsets (floats)
#define O_Z     ((size_t)0)
#define O_EX    ((size_t)262144)
#define O_EXXT  ((size_t)524288)
#define O_CROSS ((size_t)8912896)
#define O_CAT   ((size_t)17300480)
#define O_KL    ((size_t)17431536)

// scratch pseudo-slot indices (stored in O_CROSS slot tails)
#define SAGG0  0
#define SSUP0  1024
#define SHYP0  1152

// ---------------- threefry ----------------
__device__ __forceinline__ uint32_t rotl32(uint32_t v, int d){ return (v<<d)|(v>>(32-d)); }
__device__ __forceinline__ void threefry2x32(uint32_t k0, uint32_t k1, uint32_t x0, uint32_t x1,
                                             uint32_t& o0, uint32_t& o1){
  uint32_t ks2 = k0 ^ k1 ^ 0x1BD11BDAu;
  x0 += k0; x1 += k1;
  x0+=x1; x1=rotl32(x1,13); x1^=x0;  x0+=x1; x1=rotl32(x1,15); x1^=x0;
  x0+=x1; x1=rotl32(x1,26); x1^=x0;  x0+=x1; x1=rotl32(x1, 6); x1^=x0;
  x0+=k1; x1+=ks2+1u;
  x0+=x1; x1=rotl32(x1,17); x1^=x0;  x0+=x1; x1=rotl32(x1,29); x1^=x0;
  x0+=x1; x1=rotl32(x1,16); x1^=x0;  x0+=x1; x1=rotl32(x1,24); x1^=x0;
  x0+=ks2; x1+=k0+2u;
  x0+=x1; x1=rotl32(x1,13); x1^=x0;  x0+=x1; x1=rotl32(x1,15); x1^=x0;
  x0+=x1; x1=rotl32(x1,26); x1^=x0;  x0+=x1; x1=rotl32(x1, 6); x1^=x0;
  x0+=k0; x1+=k1+3u;
  x0+=x1; x1=rotl32(x1,17); x1^=x0;  x0+=x1; x1=rotl32(x1,29); x1^=x0;
  x0+=x1; x1=rotl32(x1,16); x1^=x0;  x0+=x1; x1=rotl32(x1,24); x1^=x0;
  x0+=k1; x1+=ks2+4u;
  x0+=x1; x1=rotl32(x1,13); x1^=x0;  x0+=x1; x1=rotl32(x1,15); x1^=x0;
  x0+=x1; x1=rotl32(x1,26); x1^=x0;  x0+=x1; x1=rotl32(x1, 6); x1^=x0;
  x0+=ks2; x1+=k0+5u;
  o0=x0; o1=x1;
}
__device__ __forceinline__ float tf_normal(uint32_t bits){
  float fl = __uint_as_float((bits>>9) | 0x3F800000u) - 1.0f;
  const float lo = -0.99999994f;
  float u = fmaxf(lo, fl*2.0f + lo);
  float w = -log1pf(-u*u);
  float p;
  if (w < 5.0f){
    w -= 2.5f;
    p = 2.81022636e-08f;
    p = fmaf(p,w,3.43273939e-07f); p = fmaf(p,w,-3.5233877e-06f);
    p = fmaf(p,w,-4.39150654e-06f); p = fmaf(p,w,0.00021858087f);
    p = fmaf(p,w,-0.00125372503f); p = fmaf(p,w,-0.00417768164f);
    p = fmaf(p,w,0.246640727f); p = fmaf(p,w,1.50140941f);
  } else {
    w = sqrtf(w) - 3.0f;
    p = -0.000200214257f;
    p = fmaf(p,w,0.000100950558f); p = fmaf(p,w,0.00134934322f);
    p = fmaf(p,w,-0.00367342844f); p = fmaf(p,w,0.00573950773f);
    p = fmaf(p,w,-0.0076224613f); p = fmaf(p,w,0.00943887047f);
    p = fmaf(p,w,1.00167406f); p = fmaf(p,w,2.83297682f);
  }
  return 1.4142135381698608f * (p*u);
}

// ---------------- helpers ----------------
__device__ __forceinline__ void tri_rc(int i, int& r, int& c){
  int rr = (int)((sqrtf(8.f*(float)i+1.f)-1.f)*0.5f);
  while((rr+1)*(rr+2)/2 <= i) ++rr;
  while(rr*(rr+1)/2 > i) --rr;
  r = rr; c = i - rr*(rr+1)/2;
}

__device__ __forceinline__ float dot36(const float* A, int r, const float* B, int c){
  const float4* a4 = (const float4*)(A + r*36);
  const float4* b4 = (const float4*)(B + c*36);
  float sx=0.f, sy=0.f, sz=0.f, sw=0.f;
  #pragma unroll
  for(int m=0;m<8;++m){
    float4 a=a4[m], b=b4[m];
    sx=fmaf(a.x,b.x,sx); sy=fmaf(a.y,b.y,sy);
    sz=fmaf(a.z,b.z,sz); sw=fmaf(a.w,b.w,sw);
  }
  return (sx+sy)+(sz+sw);
}
__device__ __forceinline__ void t36_rows(float* dst, const float* src, int tid){
  int r=tid>>3, c0=(tid&7)<<2;
  *(float4*)(dst + r*36 + c0) = *(const float4*)(src + r*32 + c0);
}
__device__ __forceinline__ void t36_tr(float* dst, const float* src, int tid){
  int m=tid>>3, j0=(tid&7)<<2;
  float4 v = *(const float4*)(src + m*32 + j0);
  dst[(j0+0)*36+m]=v.x; dst[(j0+1)*36+m]=v.y;
  dst[(j0+2)*36+m]=v.z; dst[(j0+3)*36+m]=v.w;
}
__device__ __forceinline__ void t36_tr36(float* dst, const float* src, int tid){
  int m=tid>>3, j0=(tid&7)<<2;
  float4 v = *(const float4*)(src + m*36 + j0);
  dst[(j0+0)*36+m]=v.x; dst[(j0+1)*36+m]=v.y;
  dst[(j0+2)*36+m]=v.z; dst[(j0+3)*36+m]=v.w;
}
__device__ __forceinline__ void t36_sym(float* dst, const float* packed, int tid){
  for(int q=tid;q<528;q+=256){
    int r,c; tri_rc(q,r,c);
    float v=packed[q];
    dst[r*36+c]=v; dst[c*36+r]=v;
  }
}

// slot IO: full 2148-float slots
__device__ __forceinline__ void ld_slot(float* dst, const float* src, int tid){
  #pragma unroll 3
  for(int q=tid;q<537;q+=256) ((float4*)dst)[q] = ((const float4*)src)[q];
}
__device__ __forceinline__ void st_slot(float* dst, const float* src, int tid){
  #pragma unroll 3
  for(int q=tid;q<537;q+=256) ((float4*)dst)[q] = ((const float4*)src)[q];
}
// scratch pseudo-slot p stored in tails (floats 560..1023) of O_CROSS slots 5p..5p+4
__device__ __forceinline__ void st_pref(float* cb, int p, const float* C, int tid){
  #pragma unroll 3
  for(int q=tid;q<537;q+=256){
    int w=q/116, o=(q-116*w)<<2;
    *(float4*)(cb + (((size_t)(5*p+w))<<10) + 560 + o) = ((const float4*)C)[q];
  }
}
__device__ __forceinline__ void ld_pref(float* C, const float* cb, int p, int tid){
  #pragma unroll 3
  for(int q=tid;q<537;q+=256){
    int w=q/116, o=(q-116*w)<<2;
    ((float4*)C)[q] = *(const float4*)(cb + (((size_t)(5*p+w))<<10) + 560 + o);
  }
}

// Fused cholesky + L^-1, quad-vectorized, stride 36.
__device__ double chol_linv36(float* W, float* Li, float* rdg, int tid){
  int r = tid>>3, c0 = (tid&7)<<2;
  {
    float4 z = make_float4(0.f,0.f,0.f,0.f);
    if(r>=c0 && r<c0+4) ((float*)&z)[r-c0]=1.f;
    *(float4*)(Li + r*36 + c0) = z;
  }
  double slog=0.0;
  for(int j=0;j<33;++j){
    if(j<32){
      float dd = W[j*36+j];
      float rd = 1.0f/sqrtf(dd);
      float invd = rd*rd;
      if(tid==0){ rdg[j]=rd; slog += (double)(0.5f*__logf(dd)); }
      if(r>j && c0+3>=j){
        float t0 = W[j*36+r]*invd;
        float4 wj  = *(const float4*)(W+j*36+c0);
        float4 cur = *(float4*)(W+r*36+c0);
        float rdl = rd;
        int c;
        c=c0;   cur.x = (c>j)? fmaf(-t0, wj.x, cur.x) : ((c==j)? cur.x*rdl : cur.x);
        c=c0+1; cur.y = (c>j)? fmaf(-t0, wj.y, cur.y) : ((c==j)? cur.y*rdl : cur.y);
        c=c0+2; cur.z = (c>j)? fmaf(-t0, wj.z, cur.z) : ((c==j)? cur.z*rdl : cur.z);
        c=c0+3; cur.w = (c>j)? fmaf(-t0, wj.w, cur.w) : ((c==j)? cur.w*rdl : cur.w);
        *(float4*)(W+r*36+c0) = cur;
      }
    }
    if(j>0){
      int ii=j-1;
      if(r>ii && c0<=ii){
        float wri = W[r*36+ii]*rdg[ii];
        float4 lrow = *(const float4*)(Li+ii*36+c0);
        float4 cur  = *(float4*)(Li+r*36+c0);
        if(c0+0<=ii) cur.x = fmaf(-wri, lrow.x, cur.x);
        if(c0+1<=ii) cur.y = fmaf(-wri, lrow.y, cur.y);
        if(c0+2<=ii) cur.z = fmaf(-wri, lrow.z, cur.z);
        if(c0+3<=ii) cur.w = fmaf(-wri, lrow.w, cur.w);
        *(float4*)(Li+r*36+c0) = cur;
      }
    }
    __syncthreads();
  }
  {
    float rr = rdg[r];
    float4 cur = *(float4*)(Li+r*36+c0);
    cur.x*=rr; cur.y*=rr; cur.z*=rr; cur.w*=rr;
    *(float4*)(Li+r*36+c0) = cur;
  }
  __syncthreads();
  return slog;
}

__device__ __forceinline__ double blk_red(double v, double* sd, int tid){
  sd[tid]=v; __syncthreads();
  for(int s=128;s>0;s>>=1){ if(tid<s) sd[tid]+=sd[tid+s]; __syncthreads(); }
  double r=sd[0]; __syncthreads(); return r;
}
__device__ double blk_logdet(float* Ms, int tid){
  double sl = 0.0;
  for (int j=0;j<Dd;++j){
    float dd = Ms[j*33+j];
    sl += log((double)dd);
    float invd = 1.0f/dd;
    #pragma unroll
    for(int p=0;p<4;p++){
      int cell = tid + (p<<8); int r=cell>>5, c=cell&31;
      if(r>j && c>j && c<=r) Ms[r*33+c] -= Ms[r*33+j]*(Ms[c*33+j]*invd);
    }
    __syncthreads();
  }
  return sl;
}

// ---------- filter-scan device pieces ----------
// unary leaf (index 0) into LDS C
__device__ void unary_f(float* C, const float* wsf, const double* wsd, int tid){
  __syncthreads();
  #pragma unroll 3
  for(int q=tid;q<528;q+=256){
    int r,c; tri_rc(q,r,c);
    C[POFF+q]=0.f;
    C[QOFF+q]=wsf[F_J0 + r*32+c];
  }
  #pragma unroll 4
  for(int q=tid;q<1024;q+=256) C[ROFF+q]=0.f;
  if(tid<32){ C[PPOFF+tid]=0.f; C[QQOFF+tid]=wsf[F_H0+tid]; }
  if(tid==0){ *(double*)(C+GAMOFF)=wsd[WSD_LOGC0]; C[FLGOFF]=1.f; }
}
// pair leaf t into LDS C
__device__ void leaf_f(float* C, int t, const float* rJ, const float* rh,
                       const float* wsf, const double* wsd, int tid){
  __syncthreads();
  #pragma unroll 3
  for(int q=tid;q<528;q+=256){
    int r,c; tri_rc(q,r,c);
    C[POFF+q] = wsf[F_ATLAMA + r*32+c] + ((r==c)?1e-6f:0.f);
    C[QOFF+q] = wsf[F_LAM + r*32+c] + rJ[(size_t)t*1024 + r*32+c];
  }
  #pragma unroll 4
  for(int q=tid;q<1024;q+=256) C[ROFF+q] = -wsf[F_ATLAM+q];
  if(tid<32){
    C[PPOFF+tid] = -wsf[F_ATLAMB+tid];
    C[QQOFF+tid] = wsf[F_LAMB+tid] + rh[(size_t)t*32+tid];
  }
  if(tid==0){
    *(double*)(C+GAMOFF) = -0.5*wsd[WSD_BTLAMB] + 0.5*wsd[WSD_LDLAM];
    C[FLGOFF]=1.f;
  }
}

// general filter combine, in-place on C (LDS); Y in LDS
__device__ void comb_f(float* C, const float* Y, float* W, float* Li, float* BA, float* BB,
                       float* rdg, float* Ls, int tid){
  __syncthreads();
  int fc=(C[FLGOFF]!=0.f), fy=(Y[FLGOFF]!=0.f);
  if(fy && !fc){
    #pragma unroll 3
    for(int q=tid;q<537;q+=256) ((float4*)C)[q]=((const float4*)Y)[q];
  } else if(fy){
    #pragma unroll 3
    for(int q=tid;q<528;q+=256){
      int r,c; tri_rc(q,r,c);
      float w = C[QOFF+q] + Y[POFF+q];
      W[r*36+c]=w; W[c*36+r]=w;
    }
    t36_rows(BA, C+ROFF, tid);
    t36_tr  (BB, Y+ROFF, tid);
    __syncthreads();
    double slog = chol_linv36(W, Li, rdg, tid);
    if(tid<32){
      float acc=0.f;
      for(int m=0;m<=tid;++m) acc=fmaf(Li[tid*36+m], C[QQOFF+m]+Y[PPOFF+m], acc);
      Ls[tid]=acc;
    }
    #pragma unroll 4
    for(int q=tid;q<1024;q+=256){ int i2=q>>5, j=q&31; W[j*36+i2]=dot36(Li,i2,BA,j); }  // T1t
    __syncthreads();
    #pragma unroll 4
    for(int q=tid;q<1024;q+=256){ int i2=q>>5, j=q&31; BA[j*36+i2]=dot36(Li,i2,BB,j); } // T2t
    __syncthreads();
    #pragma unroll 3
    for(int q=tid;q<528;q+=256){
      int r,c; tri_rc(q,r,c);
      C[POFF+q] = C[POFF+q] - dot36(W,r,W,c);
      C[QOFF+q] = Y[QOFF+q] - dot36(BA,r,BA,c);
    }
    #pragma unroll 4
    for(int q=tid;q<1024;q+=256){ int r=q>>5,c=q&31; C[ROFF+q] = -dot36(W,r,BA,c); }
    if(tid<32){
      float ap=0.f,aq=0.f;
      #pragma unroll
      for(int m=0;m<32;++m){ ap=fmaf(W[tid*36+m],Ls[m],ap); aq=fmaf(BA[tid*36+m],Ls[m],aq); }
      C[PPOFF+tid] -= ap;
      C[QQOFF+tid] = Y[QQOFF+tid] - aq;
    }
    if(tid==0){
      double g = *(double*)(C+GAMOFF) + *(const double*)(Y+GAMOFF);
      double dot=0.0;
      for(int m=0;m<32;++m) dot += (double)Ls[m]*(double)Ls[m];
      *(double*)(C+GAMOFF) = g + 0.5*dot - slog;
    }
  }
  __syncthreads();
}

// specialized advance with leaf t (shares chol with optional point output for t-1)
template<int POINT>
__device__ void adv_leaf_f(float* C, int t, const float* rJ, const float* rh,
                           const float* wsf, const double* wsd,
                           const float* CLAMA, const float* CATA, const float* catb,
                           float* W, float* Li, float* BA, float* BB,
                           float* rdg, float* Lu, float* uv, float* ev,
                           float* pe, float* outc, const float* outz, int tid){
  __syncthreads();
  #pragma unroll 3
  for(int q=tid;q<528;q+=256){
    int r,c; tri_rc(q,r,c);
    float w = C[QOFF+q] + CATA[r*36+c];
    W[r*36+c]=w; W[c*36+r]=w;
  }
  t36_rows(BB, C+ROFF, tid);
  if(tid<32){
    uv[tid] = C[QQOFF+tid] - catb[tid];
    if(POINT) ev[tid] = outz[(size_t)(t-1)*32+tid];
  }
  __syncthreads();
  double slog = chol_linv36(W, Li, rdg, tid);
  if(tid<32){
    float acc=0.f;
    for(int m=0;m<=tid;++m) acc=fmaf(Li[tid*36+m], uv[m], acc);
    Lu[tid]=acc;
  }
  #pragma unroll 4
  for(int q=tid;q<1024;q+=256){ int i2=q>>5, j=q&31; W[j*36+i2]=dot36(Li,i2,BB,j); }    // T1t
  __syncthreads();
  #pragma unroll 4
  for(int q=tid;q<1024;q+=256){ int i2=q>>5, j=q&31; BA[j*36+i2]=dot36(Li,i2,CLAMA,j); } // TA
  __syncthreads();
  if(POINT){
    t36_tr36(BB, Li, tid);    // BB = LiT rows (C.R rows dead: consumed into T1t)
    __syncthreads();
    #pragma unroll 4
    for(int q=tid;q<1024;q+=256){ int r=q>>5,c=q&31; pe[BG+q]=dot36(BB,r,BA,c); }
    #pragma unroll 3
    for(int q=tid;q<528;q+=256){ int r,c; tri_rc(q,r,c); float a=dot36(BB,r,BB,c); pe[BP+q]=a; outc[q]=a; }
    if(tid<32){
      float ag=0.f, ay=0.f;
      for(int m2=tid;m2<32;++m2){ float lv=Li[m2*36+tid]; ag=fmaf(lv,Lu[m2],ag); ay=fmaf(lv,ev[m2],ay); }
      pe[BCM+tid]=ag; pe[BCZ+tid]=ag+ay; outc[528+tid]=ag;
    }
    if(tid==0) pe[FLGOFF]=1.f;
  }
  // advance writes (in-place on C)
  #pragma unroll 3
  for(int q=tid;q<528;q+=256){
    int r,c; tri_rc(q,r,c);
    C[POFF+q] = C[POFF+q] - dot36(W,r,W,c);
    C[QOFF+q] = (wsf[F_LAM + r*32+c] + rJ[(size_t)t*1024 + r*32+c]) - dot36(BA,r,BA,c);
  }
  #pragma unroll 4
  for(int q=tid;q<1024;q+=256){ int r=q>>5,c=q&31; C[ROFF+q] = dot36(W,r,BA,c); }
  if(tid<32){
    float ap=0.f,aq=0.f;
    #pragma unroll
    for(int m=0;m<32;++m){ ap=fmaf(W[tid*36+m],Lu[m],ap); aq=fmaf(BA[tid*36+m],Lu[m],aq); }
    C[PPOFF+tid] -= ap;
    C[QQOFF+tid] = (wsf[F_LAMB+tid] + rh[(size_t)t*32+tid]) + aq;
  }
  if(tid==0){
    double dot=0.0;
    for(int m=0;m<32;++m) dot += (double)Lu[m]*(double)Lu[m];
    *(double*)(C+GAMOFF) += (-0.5*wsd[WSD_BTLAMB] + 0.5*wsd[WSD_LDLAM]) + 0.5*dot - slog;
  }
}

// final-state from total C (block 1023 of kf_prop)
__device__ void final_f(float* C, float* W, float* Li, float* BB,
                        float* rdg, float* Lu, float* uv, float* ev, float* gv,
                        float* wsf, double* wsd, float* out, int tid){
  __syncthreads();
  #pragma unroll 3
  for(int q=tid;q<528;q+=256){
    int r,c; tri_rc(q,r,c);
    float w = C[QOFF+q] + ((r==c)?1e-6f:0.f);
    W[r*36+c]=w; W[c*36+r]=w;
  }
  if(tid<32){ uv[tid]=C[QQOFF+tid]; ev[tid]=out[O_Z+(size_t)NN*32+tid]; }
  __syncthreads();
  double slog2 = chol_linv36(W, Li, rdg, tid);
  if(tid<32){
    float acc=0.f;
    for(int m=0;m<=tid;++m) acc=fmaf(Li[tid*36+m], uv[m], acc);
    Lu[tid]=acc;
  }
  t36_tr36(BB, Li, tid);
  __syncthreads();
  if(tid<32){
    float am=0.f, ay=0.f;
    for(int m2=tid;m2<32;++m2){ float lv=Li[m2*36+tid]; am=fmaf(lv,Lu[m2],am); ay=fmaf(lv,ev[m2],ay); }
    gv[tid]=am;
    wsf[F_MLAST+tid]=am; out[O_EX+(size_t)NN*32+tid]=am;
    float xt=am+ay;
    wsf[F_XT+tid]=xt; out[O_Z+(size_t)NN*32+tid]=xt;
  }
  __syncthreads();
  #pragma unroll 4
  for(int q=tid;q<1024;q+=256){
    int r=q>>5,c=q&31;
    float a = dot36(BB,r,BB,c);
    wsf[F_COVT+q]=a;
    out[O_EXXT+(size_t)NN*1024+q]=a+gv[r]*gv[c];
  }
  if(tid==0){
    double gam=*(double*)(C+GAMOFF);
    double hm=0.0;
    for(int m=0;m<32;++m) hm += (double)uv[m]*(double)gv[m];
    wsd[WSD_LOGZQ] = gam + 0.5*hm + 0.5*Dd*LOG2PI_ - slog2;
  }
}

// ---------- affine-scan device pieces ----------
// general affine combine, in-place on C; result = Y∘X (C earlier, Y later)
__device__ void comb_a(float* C, const float* Y, float* B1, float* B2, float* B3, float* B4,
                       float* vcz, float* vcm, int tid){
  __syncthreads();
  int fc=(C[FLGOFF]!=0.f), fy=(Y[FLGOFF]!=0.f);
  if(fy && !fc){
    #pragma unroll 3
    for(int q=tid;q<537;q+=256) ((float4*)C)[q]=((const float4*)Y)[q];
  } else if(fy){
    t36_rows(B1, Y+BG, tid);
    t36_tr  (B3, C+BG, tid);
    t36_sym (B4, C+BP, tid);
    if(tid<32){ vcz[tid]=C[BCZ+tid]; vcm[tid]=C[BCM+tid]; }
    __syncthreads();
    #pragma unroll 4
    for(int q=tid;q<1024;q+=256){ int r=q>>5,c=q&31; C[BG+q]=dot36(B1,r,B3,c); }
    #pragma unroll 4
    for(int q=tid;q<1024;q+=256){ int r=q>>5,c=q&31; B2[r*36+c]=dot36(B1,r,B4,c); }
    __syncthreads();
    #pragma unroll 3
    for(int q=tid;q<528;q+=256){ int r,c; tri_rc(q,r,c); C[BP+q]=dot36(B2,r,B1,c)+Y[BP+q]; }
    if(tid<32){
      float az=0.f,am=0.f;
      #pragma unroll
      for(int m=0;m<32;++m){ float g=B1[tid*36+m]; az=fmaf(g,vcz[m],az); am=fmaf(g,vcm[m],am); }
      C[BCZ+tid]=az+Y[BCZ+tid];
      C[BCM+tid]=am+Y[BCM+tid];
    }
  }
  __syncthreads();
}

// ---------------- setup: 19 independent blocks (unchanged) ----------------
__global__ __launch_bounds__(256) void k_setup(const float* rJ, const float* rh, const float* loc,
    const float* Tp, const float* Lp, const float* X, const float* plam, const float* pX,
    const float* ptau, const float* pmu, float* wsf, double* wsd){
  __shared__ float s1[1056], s2[1056], s3[1056];
  __shared__ float sv[32], sv2[32];
  int tid=threadIdx.x; int b=blockIdx.x;
  if(b==0){
    for(int p=0;p<4;p++){int cell=tid+(p<<8);int r=cell>>5,c=cell&31; s1[r*33+c]=Tp[cell];}
    if(tid<32) sv[tid]=loc[tid];
    __syncthreads();
    for(int p=0;p<4;p++){int cell=tid+(p<<8);int r=cell>>5,c=cell&31;
      float a=0.f;
      #pragma unroll
      for(int m=0;m<Dd;++m) a=fmaf(s1[r*33+m], s1[c*33+m], a);
      if(r==c) a+=1e-8f;
      s2[r*33+c]=a; wsf[F_TAU+cell]=a; wsf[F_J0+cell]=a+rJ[cell];
    }
    __syncthreads();
    if(tid<32){ float tm=0.f;
      #pragma unroll
      for(int m=0;m<Dd;++m) tm=fmaf(s2[tid*33+m], sv[m], tm);
      sv2[tid]=tm; wsf[F_TAUMU+tid]=tm; wsf[F_H0+tid]=tm+rh[tid];
    }
    __syncthreads();
    double ldt = blk_logdet(s2, tid);
    if(tid==0){ double dd=0; for(int m=0;m<Dd;++m) dd += (double)sv[m]*(double)sv2[m];
      wsd[WSD_LOGC0] = -0.5*dd + 0.5*ldt - 0.5*Dd*LOG2PI_; }
  } else if(b==1){
    for(int p=0;p<4;p++){int cell=tid+(p<<8);int r=cell>>5,c=cell&31; s1[r*33+c]=Lp[cell];}
    __syncthreads();
    for(int p=0;p<4;p++){int cell=tid+(p<<8);int r=cell>>5,c=cell&31;
      float a=0.f;
      #pragma unroll
      for(int m=0;m<Dd;++m) a=fmaf(s1[r*33+m], s1[c*33+m], a);
      if(r==c) a+=1e-8f;
      s2[r*33+c]=a; wsf[F_LAM+cell]=a;
    }
    __syncthreads();
    for(int p=0;p<4;p++){int cell=tid+(p<<8);int r=cell>>5,c=cell&31;
      float a=X[r*33+c]; s3[r*33+c]=a; wsf[F_A+cell]=a; }
    if(tid<32){ sv[tid]=X[tid*33+32]; wsf[F_B+tid]=sv[tid]; }
    __syncthreads();
    for(int p=0;p<4;p++){int cell=tid+(p<<8);int r=cell>>5,c=cell&31;
      float a=0.f,b2=0.f;
      #pragma unroll
      for(int m=0;m<Dd;++m){ a=fmaf(s2[r*33+m], s3[m*33+c], a); b2=fmaf(s3[m*33+r], s2[m*33+c], b2); }
      s1[r*33+c]=a; wsf[F_LAMA+cell]=a; wsf[F_ATLAM+cell]=b2;
    }
    if(tid<32){ float lb=0.f;
      #pragma unroll
      for(int m=0;m<Dd;++m) lb=fmaf(s2[tid*33+m], sv[m], lb);
      sv2[tid]=lb; wsf[F_LAMB+tid]=lb;
    }
    __syncthreads();
    for(int p=0;p<4;p++){int cell=tid+(p<<8);int r=cell>>5,c=cell&31;
      float a=0.f;
      #pragma unroll
      for(int m=0;m<Dd;++m) a=fmaf(s3[m*33+r], s1[m*33+c], a);
      wsf[F_ATLAMA+cell]=a;
    }
    if(tid<32){ float ab=0.f;
      #pragma unroll
      for(int m=0;m<Dd;++m) ab=fmaf(s3[m*33+tid], sv2[m], ab);
      wsf[F_ATLAMB+tid]=ab;
    }
    if(tid==0){ double bb=0; for(int m=0;m<Dd;++m) bb += (double)sv[m]*(double)sv2[m];
      wsd[WSD_BTLAMB]=bb; }
    __syncthreads();
    double ldl = blk_logdet(s2, tid);
    if(tid==0) wsd[WSD_LDLAM]=ldl;
  } else if(b==2){
    for(int p=0;p<4;p++){int cell=tid+(p<<8);int r=cell>>5,c=cell&31; s1[r*33+c]=ptau[cell];}
    if(tid<32) sv[tid]=pmu[tid];
    __syncthreads();
    if(tid<32){ float tm=0.f;
      #pragma unroll
      for(int m=0;m<Dd;++m) tm=fmaf(s1[tid*33+m], sv[m], tm);
      sv2[tid]=tm; wsf[F_TPM+tid]=tm;
    }
    __syncthreads();
    double ldp = blk_logdet(s1, tid);
    if(tid==0){ double dd=0; for(int m=0;m<Dd;++m) dd += (double)sv[m]*(double)sv2[m];
      wsd[WSD_MIXC] = -0.5*dd + 0.5*ldp - 0.5*Dd*LOG2PI_; }
  } else {
    int k2 = b-3;
    for(int p=0;p<4;p++){int cell=tid+(p<<8);int r=cell>>5,c=cell&31;
      s2[r*33+c]=plam[k2*1024+cell]; s3[r*33+c]=pX[k2*1056 + r*33 + c];}
    if(tid<32) sv[tid]=pX[k2*1056 + tid*33 + 32];
    __syncthreads();
    for(int p=0;p<4;p++){int cell=tid+(p<<8);int r=cell>>5,c=cell&31;
      float a=0.f;
      #pragma unroll
      for(int m=0;m<Dd;++m) a=fmaf(s2[r*33+m], s3[m*33+c], a);
      s1[r*33+c]=a; wsf[F_LAMAK + (size_t)k2*1024 + cell]=a;
    }
    if(tid<32){ float lb=0.f;
      #pragma unroll
      for(int m=0;m<Dd;++m) lb=fmaf(s2[tid*33+m], sv[m], lb);
      sv2[tid]=lb; wsf[F_LAMBK + k2*32 + tid]=lb;
    }
    __syncthreads();
    for(int p=0;p<4;p++){int cell=tid+(p<<8);int r=cell>>5,c=cell&31;
      float a=0.f;
      #pragma unroll
      for(int m=0;m<Dd;++m) a=fmaf(s3[m*33+r], s1[m*33+c], a);
      wsf[F_ATLAMAK + (size_t)k2*1024 + cell]=a;
    }
    if(tid<32){ float ab=0.f;
      #pragma unroll
      for(int m=0;m<Dd;++m) ab=fmaf(s3[m*33+tid], sv2[m], ab);
      wsf[F_ATLAMBK + k2*32 + tid]=ab;
    }
    if(tid==0){ float bb=0.f; for(int m=0;m<Dd;++m) bb=fmaf(sv[m],sv2[m],bb);
      wsf[F_BTLAMBK + k2]=bb; }
    __syncthreads();
    double dk = blk_logdet(s2, tid);
    if(tid==0) wsf[F_LOGDETK + k2]=(float)dk;
  }
}

// ---------------- eps ----------------
__global__ __launch_bounds__(256) void k_eps(const int* seedp, float* outz){
  uint32_t seed = (uint32_t)seedp[0];
  uint32_t K0,K1;
  threefry2x32(0u, seed, 0u, 1u, K0, K1);
  uint32_t i = blockIdx.x*256u + threadIdx.x;
  uint32_t o0,o1;
  threefry2x32(K0, K1, 0u, i, o0, o1);
  outz[i] = tf_normal(o0 ^ o1);
}

// ---------------- HMM (unchanged) ----------------
__global__ __launch_bounds__(256) void k_hmmpow(const float* tl, float* wsf){
  __shared__ float A0[256], A1[256];
  int tid=threadIdx.x;
  A0[tid]=tl[tid];
  wsf[F_TPOW+tid]=A0[tid];
  __syncthreads();
  float* cur=A0; float* nxt=A1;
  for(int k=1;k<13;++k){
    int i=tid>>4, j=tid&15;
    float mx=-3.0e38f;
    #pragma unroll
    for(int m=0;m<16;++m) mx=fmaxf(mx, cur[i*16+m]+cur[m*16+j]);
    float s=0.f;
    #pragma unroll
    for(int m=0;m<16;++m) s+=__expf(cur[i*16+m]+cur[m*16+j]-mx);
    float v=mx+__logf(s);
    nxt[tid]=v; wsf[F_TPOW+k*256+tid]=v;
    __syncthreads();
    float* t2=cur; cur=nxt; nxt=t2;
  }
}

__global__ __launch_bounds__(256) void k_hmmab(const float* il, float* wsf){
  __shared__ float S[3328];
  int tid=threadIdx.x;
  for(int p=0;p<13;++p) S[p*256+tid]=wsf[F_TPOW+p*256+tid];
  __syncthreads();
  int n = blockIdx.x*256 + tid;
  if(n>NN-1) return;
  float v[16], w[16];
  #pragma unroll
  for(int j=0;j<16;++j) v[j]=il[j];
  for(int k=0;k<13;++k){
    if((n>>k)&1){
      #pragma unroll
      for(int j=0;j<16;++j){
        float mx=-3.0e38f;
        #pragma unroll
        for(int i2=0;i2<16;++i2) mx=fmaxf(mx, v[i2]+S[k*256+i2*16+j]);
        float s=0.f;
        #pragma unroll
        for(int i2=0;i2<16;++i2) s+=__expf(v[i2]+S[k*256+i2*16+j]-mx);
        w[j]=mx+__logf(s);
      }
      #pragma unroll
      for(int j=0;j<16;++j) v[j]=w[j];
    }
  }
  #pragma unroll
  for(int j=0;j<16;++j) wsf[F_ALPHA+(size_t)n*16+j]=v[j];
  if(n==NN-1){
    float mx=-3.0e38f;
    #pragma unroll
    for(int j=0;j<16;++j) mx=fmaxf(mx,v[j]);
    float s=0.f;
    #pragma unroll
    for(int j=0;j<16;++j) s+=__expf(v[j]-mx);
    wsf[F_SC+0]=mx+__logf(s);
  }
  int m = NN-1-n;
  float b[16];
  #pragma unroll
  for(int i2=0;i2<16;++i2) b[i2]=0.f;
  for(int k=0;k<13;++k){
    if((m>>k)&1){
      #pragma unroll
      for(int i2=0;i2<16;++i2){
        float mx=-3.0e38f;
        #pragma unroll
        for(int j=0;j<16;++j) mx=fmaxf(mx, S[k*256+i2*16+j]+b[j]);
        float s=0.f;
        #pragma unroll
        for(int j=0;j<16;++j) s+=__expf(S[k*256+i2*16+j]+b[j]-mx);
        w[i2]=mx+__logf(s);
      }
      #pragma unroll
      for(int i2=0;i2<16;++i2) b[i2]=w[i2];
    }
  }
  #pragma unroll
  for(int i2=0;i2<16;++i2) wsf[F_BETA+(size_t)n*16+i2]=b[i2];
}

__global__ __launch_bounds__(256) void k_cat(const float* tl, float* wsf, float* out){
  __shared__ float Ts[256]; __shared__ float al[1024]; __shared__ float be[1040];
  int tid=threadIdx.x;
  Ts[tid]=tl[tid];
  float logZ = wsf[F_SC+0];
  int n0=blockIdx.x*64;
  for(int q=tid;q<1024;q+=256){ int n=n0+(q>>4); al[q] = (n<NN)? wsf[F_ALPHA+(size_t)n*16+(q&15)] : 0.f; }
  for(int q=tid;q<1040;q+=256){ int n=n0+(q>>4); be[q] = (n<NN)? wsf[F_BETA +(size_t)n*16+(q&15)] : 0.f; }
  __syncthreads();
  for(int q=tid;q<1024;q+=256){ int n=n0+(q>>4);
    if(n<NN) out[O_CAT+(size_t)n*16+(q&15)] = __expf(al[q]+be[q]-logZ); }
  int i=tid>>4, j=tid&15;
  float acc=0.f;
  #pragma unroll 4
  for(int nn=0;nn<64;++nn){
    int n=n0+nn;
    if(n<NN-1) acc += __expf(al[nn*16+i]+Ts[i*16+j]+be[(nn+1)*16+j]-logZ);
  }
  wsf[F_EZ + blockIdx.x*256 + tid]=acc;
}

// ---------------- F1: chunk aggregates ----------------
__global__ __launch_bounds__(256,4) void kf_agg(const float* rJ, const float* rh,
                                                float* wsf, double* wsd, float* out){
  __shared__ __align__(16) float C[2148];
  __shared__ __align__(16) float W[1152], Li[1152], BA[1152], BB[1152], CLAMA[1152], CATA[1152];
  __shared__ float rdg[32], Lu[32], uv[32], ev[32], catb[32];
  int tid=threadIdx.x; int i=blockIdx.x;
  if(i==0 && tid==0) wsf[F_SCAN+FLGOFF]=0.f;   // slot 0 = affine pad (flag 0)
  t36_rows(CLAMA, wsf+F_LAMA, tid);
  for(int q=tid;q<528;q+=256){ int r,c; tri_rc(q,r,c);
    float v=wsf[F_ATLAMA+r*32+c]+((r==c)?1e-6f:0.f); CATA[r*36+c]=v; CATA[c*36+r]=v; }
  if(tid<32) catb[tid]=wsf[F_ATLAMB+tid];
  if(i==0) unary_f(C, wsf, wsd, tid);
  else     leaf_f(C, 8*i, rJ, rh, wsf, wsd, tid);
  for(int e=1;e<8;++e)
    adv_leaf_f<0>(C, 8*i+e, rJ, rh, wsf, wsd, CLAMA, CATA, catb,
                  W,Li,BA,BB, rdg,Lu,uv,ev, (float*)0, (float*)0, (const float*)0, tid);
  __syncthreads();
  st_pref(out + O_CROSS, SAGG0+i, C, tid);
}

// ---------------- F2: pyramid over scratch pseudo-slots ----------------
__global__ __launch_bounds__(256,4) void kf_seq(float* out, int in0, int out0){
  __shared__ __align__(16) float C[2148], Y[2148];
  __shared__ __align__(16) float W[1152], Li[1152], BA[1152], BB[1152];
  __shared__ float rdg[32], Ls[32];
  int tid=threadIdx.x; int i=blockIdx.x;
  float* cb = out + O_CROSS;
  ld_pref(C, cb, in0+8*i, tid);
  for(int e=1;e<8;++e){
    ld_pref(Y, cb, in0+8*i+e, tid);
    comb_f(C, Y, W,Li,BA,BB, rdg,Ls, tid);
  }
  __syncthreads();
  st_pref(cb, out0+i, C, tid);
}
__global__ __launch_bounds__(256,4) void kf_sqx(float* out, int base, int n){
  __shared__ __align__(16) float C[2148], Y[2148];
  __shared__ __align__(16) float W[1152], Li[1152], BA[1152], BB[1152];
  __shared__ float rdg[32], Ls[32];
  int tid=threadIdx.x;
  float* cb = out + O_CROSS;
  if(tid==0) C[FLGOFF]=0.f;
  for(int e=0;e<n;++e){
    ld_pref(Y, cb, base+e, tid);
    __syncthreads();
    st_pref(cb, base+e, C, tid);
    comb_f(C, Y, W,Li,BA,BB, rdg,Ls, tid);
  }
}
__global__ __launch_bounds__(256,4) void kf_sqp(float* out, int pre0, int el0){
  __shared__ __align__(16) float C[2148], Y[2148];
  __shared__ __align__(16) float W[1152], Li[1152], BA[1152], BB[1152];
  __shared__ float rdg[32], Ls[32];
  int tid=threadIdx.x; int i=blockIdx.x;
  float* cb = out + O_CROSS;
  ld_pref(C, cb, pre0+i, tid);
  for(int e=0;e<8;++e){
    ld_pref(Y, cb, el0+8*i+e, tid);
    __syncthreads();
    st_pref(cb, el0+8*i+e, C, tid);
    comb_f(C, Y, W,Li,BA,BB, rdg,Ls, tid);
  }
}

// ---------------- F3: propagate + fused point ----------------
__global__ __launch_bounds__(256,4) void kf_prop(const float* rJ, const float* rh,
                                                 float* wsf, double* wsd, float* out){
  __shared__ __align__(16) float C[2148];
  __shared__ __align__(16) float W[1152], Li[1152], BA[1152], BB[1152], CLAMA[1152], CATA[1152];
  __shared__ float rdg[32], Lu[32], uv[32], ev[32], catb[32], gv[32];
  int tid=threadIdx.x; int i=blockIdx.x;
  float* cb = out + O_CROSS;
  ld_pref(C, cb, SAGG0+i, tid);
  t36_rows(CLAMA, wsf+F_LAMA, tid);
  for(int q=tid;q<528;q+=256){ int r,c; tri_rc(q,r,c);
    float v=wsf[F_ATLAMA+r*32+c]+((r==c)?1e-6f:0.f); CATA[r*36+c]=v; CATA[c*36+r]=v; }
  if(tid<32) catb[tid]=wsf[F_ATLAMB+tid];
  for(int e=0;e<8;++e){
    int j=8*i+e;
    if(j==0){
      unary_f(C, wsf, wsd, tid);
    } else {
      adv_leaf_f<1>(C, j, rJ, rh, wsf, wsd, CLAMA, CATA, catb,
                    W,Li,BA,BB, rdg,Lu,uv,ev,
                    wsf + F_SCAN + (size_t)j*SSTR,
                    out + O_CROSS + (size_t)(j-1)*1024,
                    out + O_Z, tid);
    }
  }
  if(i==1023) final_f(C, W,Li,BB, rdg,Lu,uv,ev,gv, wsf, wsd, out, tid);
}

// ---------------- A1: affine chunk aggregates ----------------
__global__ __launch_bounds__(256,4) void ka_agg(float* wsf, float* out){
  __shared__ __align__(16) float C[2148], Y[2148];
  __shared__ __align__(16) float B1[1152], B2[1152], B3[1152], B4[1152];
  __shared__ float vcz[32], vcm[32];
  int tid=threadIdx.x; int i=blockIdx.x;
  ld_slot(C, wsf + F_SCAN + (size_t)(NN-8*i)*SSTR, tid);
  for(int e=1;e<8;++e){
    int j=8*i+e; int s=(j<NN)? (NN-j) : 0;
    ld_slot(Y, wsf + F_SCAN + (size_t)s*SSTR, tid);
    comb_a(C, Y, B1,B2,B3,B4, vcz,vcm, tid);
  }
  __syncthreads();
  st_pref(out + O_CROSS, SAGG0+i, C, tid);
}

// ---------------- A2: pyramid ----------------
__global__ __launch_bounds__(256,4) void ka_seq(float* out, int in0, int out0){
  __shared__ __align__(16) float C[2148], Y[2148];
  __shared__ __align__(16) float B1[1152], B2[1152], B3[1152], B4[1152];
  __shared__ float vcz[32], vcm[32];
  int tid=threadIdx.x; int i=blockIdx.x;
  float* cb = out + O_CROSS;
  ld_pref(C, cb, in0+8*i, tid);
  for(int e=1;e<8;++e){
    ld_pref(Y, cb, in0+8*i+e, tid);
    comb_a(C, Y, B1,B2,B3,B4, vcz,vcm, tid);
  }
  __syncthreads();
  st_pref(cb, out0+i, C, tid);
}
__global__ __launch_bounds__(256,4) void ka_sqx(float* out, int base, int n){
  __shared__ __align__(16) float C[2148], Y[2148];
  __shared__ __align__(16) float B1[1152], B2[1152], B3[1152], B4[1152];
  __shared__ float vcz[32], vcm[32];
  int tid=threadIdx.x;
  float* cb = out + O_CROSS;
  if(tid==0) C[FLGOFF]=0.f;
  for(int e=0;e<n;++e){
    ld_pref(Y, cb, base+e, tid);
    __syncthreads();
    st_pref(cb, base+e, C, tid);
    comb_a(C, Y, B1,B2,B3,B4, vcz,vcm, tid);
  }
}
__global__ __launch_bounds__(256,4) void ka_sqp(float* out, int pre0, int el0){
  __shared__ __align__(16) float C[2148], Y[2148];
  __shared__ __align__(16) float B1[1152], B2[1152], B3[1152], B4[1152];
  __shared__ float vcz[32], vcm[32];
  int tid=threadIdx.x; int i=blockIdx.x;
  float* cb = out + O_CROSS;
  ld_pref(C, cb, pre0+i, tid);
  for(int e=0;e<8;++e){
    ld_pref(Y, cb, el0+8*i+e, tid);
    __syncthreads();
    st_pref(cb, el0+8*i+e, C, tid);
    comb_a(C, Y, B1,B2,B3,B4, vcz,vcm, tid);
  }
}

// ---------------- A3: propagate + fused apply (smoother/sampler outputs) ----------------
__global__ __launch_bounds__(256,4) void ka_prop(float* wsf, float* out){
  __shared__ __align__(16) float C[2148], Y[2148];
  __shared__ __align__(16) float B1[1152], B2[1152], B3[1152], B4[1152];
  __shared__ float vcz[32], vcm[32], mlv[32], xtv[32], mv[32];
  int tid=threadIdx.x; int i=blockIdx.x;
  ld_pref(C, out + O_CROSS, SAGG0+i, tid);
  if(tid<32){ mlv[tid]=wsf[F_MLAST+tid]; xtv[tid]=wsf[F_XT+tid]; }
  __syncthreads();
  for(int e=0;e<8;++e){
    int j=8*i+e;
    if(j>0){
      int t=NN-j;
      // apply composite C -> m_t, z_t, ExxT_t
      t36_rows(B1, C+BG, tid);
      t36_rows(B4, wsf+F_COVT, tid);
      __syncthreads();
      if(tid<32){
        float am=0.f, az=0.f;
        #pragma unroll
        for(int m=0;m<32;++m){ float g=B1[tid*36+m]; am=fmaf(g,mlv[m],am); az=fmaf(g,xtv[m],az); }
        mv[tid]=am+C[BCM+tid];
        out[O_EX+(size_t)t*32+tid]=mv[tid];
        out[O_Z +(size_t)t*32+tid]=az+C[BCZ+tid];
      }
      #pragma unroll 4
      for(int q=tid;q<1024;q+=256){ int r=q>>5,c=q&31; B2[r*36+c]=dot36(B1,r,B4,c); }
      __syncthreads();
      #pragma unroll 3
      for(int q=tid;q<528;q+=256){
        int r,c; tri_rc(q,r,c);
        float e2 = dot36(B2,r,B1,c) + C[BP+q] + mv[r]*mv[c];
        out[O_EXXT+(size_t)t*1024 + r*32+c]=e2;
        if(r!=c) out[O_EXXT+(size_t)t*1024 + c*32+r]=e2;
      }
    }
    int s=(j<NN)? (NN-j) : 0;
    ld_slot(Y, wsf + F_SCAN + (size_t)s*SSTR, tid);
    comb_a(C, Y, B1,B2,B3,B4, vcz,vcm, tid);
  }
}

// ---------------- Cross_t (unchanged) ----------------
__global__ __launch_bounds__(256,6) void k_cross(float* wsf, float* out){
  __shared__ __align__(16) float PV36[1152], LA36[1152], E136[1152], GF36[1152];
  __shared__ float gv[32], m1[32];
  int tid=threadIdx.x;
  int t = blockIdx.x;
  float* outc = out + O_CROSS + (size_t)t*1024;
  t36_sym (PV36, outc, tid);
  t36_rows(LA36, wsf+F_LAMA, tid);
  t36_rows(E136, out+O_EXXT+(size_t)(t+1)*1024, tid);
  if(tid<32){ gv[tid]=outc[528+tid]; m1[tid]=out[O_EX+(size_t)(t+1)*32+tid]; }
  __syncthreads();
  #pragma unroll 4
  for(int q=tid;q<1024;q+=256){
    int r=q>>5,c=q&31;
    GF36[r*36+c] = dot36(PV36, r, LA36, c);
  }
  __syncthreads();
  #pragma unroll 4
  for(int q=tid;q<1024;q+=256){
    int i2=q>>5, j=q&31;
    float acc = dot36(GF36, j, E136, i2);
    outc[q] = acc + gv[j]*m1[i2];
  }
}

// ---------------- big reduction over t (unchanged) ----------------
__global__ __launch_bounds__(256) void k_terms(const float* rJ, const float* rh,
    const float* plam, float* wsf, double* wsd, float* out){
  __shared__ float slam[1056], slamA[1056], sata[1056];
  __shared__ float slamb[32], satlb[32], cst[16], sw[16];
  __shared__ double sd[256];
  int tid=threadIdx.x; int i8=tid>>3, c4=(tid&7)*4;
  for(int p=0;p<4;p++){int cell=tid+(p<<8);int r=cell>>5,c=cell&31;
    slam[r*33+c]=wsf[F_LAM+cell]; slamA[r*33+c]=wsf[F_LAMA+cell]; sata[r*33+c]=wsf[F_ATLAMA+cell];}
  if(tid<32){slamb[tid]=wsf[F_LAMB+tid]; satlb[tid]=wsf[F_ATLAMB+tid];}
  if(tid<16) cst[tid] = -0.5f*wsf[F_BTLAMBK+tid] + 0.5f*wsf[F_LOGDETK+tid];
  __syncthreads();
  double dr=0.0, dt=0.0, dm=0.0;
  int t0=blockIdx.x*8;
  for(int tt=0;tt<8;++tt){
    int t=t0+tt;
    if(t<NN){ if(tid<16) sw[tid]=out[O_CAT+(size_t)t*16+tid]; }
    __syncthreads();
    size_t cb=(size_t)t*1024+((size_t)i8<<5)+c4;
    float4 exT=*(const float4*)(out+O_EXXT+cb);
    float4 rj =*(const float4*)(rJ+cb);
    dr += -0.5*(double)(rj.x*exT.x+rj.y*exT.y+rj.z*exT.z+rj.w*exT.w);
    if(tid<32) dr += (double)(rh[(size_t)t*32+tid]*out[O_EX+(size_t)t*32+tid]);
    if(t>=1){
      dt += -0.5*(double)(slam[i8*33+c4]*exT.x + slam[i8*33+c4+1]*exT.y
                        + slam[i8*33+c4+2]*exT.z + slam[i8*33+c4+3]*exT.w);
      if(tid<32) dt += (double)(slamb[tid]*out[O_EX+(size_t)t*32+tid]);
    }
    if(t<NN){
      float4 crT =*(const float4*)(out+O_CROSS+cb);
      float4 exT1=*(const float4*)(out+O_EXXT+cb+1024);
      dt += (double)(slamA[i8*33+c4]*crT.x + slamA[i8*33+c4+1]*crT.y
                   + slamA[i8*33+c4+2]*crT.z + slamA[i8*33+c4+3]*crT.w)
          -0.5*(double)(sata[i8*33+c4]*exT.x + sata[i8*33+c4+1]*exT.y
                      + sata[i8*33+c4+2]*exT.z + sata[i8*33+c4+3]*exT.w);
      if(tid<32) dt -= (double)(satlb[tid]*out[O_EX+(size_t)t*32+tid]);
      const float* pe1=(const float*)&exT1; const float* pcr=(const float*)&crT; const float* pe0=(const float*)&exT;
      #pragma unroll
      for(int q=0;q<4;q++){
        int cc=(i8<<5)+c4+q;
        float wl=0.f, wa=0.f, wt2=0.f;
        #pragma unroll
        for(int k2=0;k2<KK;k2++){ float wv=sw[k2];
          wl =fmaf(wv, plam[(size_t)k2*1024+cc], wl);
          wa =fmaf(wv, wsf[F_LAMAK+(size_t)k2*1024+cc], wa);
          wt2=fmaf(wv, wsf[F_ATLAMAK+(size_t)k2*1024+cc], wt2);}
        dm += (double)(-0.5f*wl*pe1[q] + wa*pcr[q] - 0.5f*wt2*pe0[q]);
      }
      if(tid<32){
        float wlb=0.f, wtb=0.f;
        #pragma unroll
        for(int k2=0;k2<KK;k2++){ wlb=fmaf(sw[k2], wsf[F_LAMBK+k2*32+tid], wlb);
                                  wtb=fmaf(sw[k2], wsf[F_ATLAMBK+k2*32+tid], wtb);}
        dm += (double)(wlb*out[O_EX+(size_t)(t+1)*32+tid] - wtb*out[O_EX+(size_t)t*32+tid]);
      }
      if(tid<16) dm += (double)(sw[tid]*cst[tid]);
    }
    __syncthreads();
  }
  double r1=blk_red(dr,sd,tid);
  double r2=blk_red(dt,sd,tid);
  double r3=blk_red(dm,sd,tid);
  if(tid==0){ wsd[WSD_PR+blockIdx.x]=r1; wsd[WSD_PT+blockIdx.x]=r2; wsd[WSD_PM+blockIdx.x]=r3; }
}

__global__ __launch_bounds__(256) void k_final(const float* il, const float* tl,
    const float* ilp, const float* tlp, const float* ptau, float* wsf, double* wsd, float* out){
  __shared__ double sd[256];
  int tid=threadIdx.x;
  double ez=0.0;
  for(int b=0;b<128;++b) ez += (double)wsf[F_EZ + b*256 + tid];
  double v = ez * (double)(tl[tid]-tlp[tid]);
  if(tid<16) v += (double)out[O_CAT+tid] * (double)(il[tid]-ilp[tid]);
  double hmmkl = blk_red(v, sd, tid) - (double)wsf[F_SC+0];
  double a=0,b2=0,c=0;
  for(int q=0;q<4;q++){int b3=tid+q*256; a+=wsd[WSD_PR+b3]; b2+=wsd[WSD_PT+b3]; c+=wsd[WSD_PM+b3];}
  double recog=blk_red(a,sd,tid), trns=blk_red(b2,sd,tid), mixt=blk_red(c,sd,tid);
  double ia=0, ib=0, va=0, vb=0;
  for(int p=0;p<4;p++){int cell=tid+(p<<8);
    float e0=out[O_EXXT+cell];
    ia += (double)(wsf[F_TAU+cell]*e0);
    ib += (double)(ptau[cell]*e0);
  }
  if(tid<32){ float ex0=out[O_EX+tid];
    va=(double)(ex0*wsf[F_TAUMU+tid]); vb=(double)(ex0*wsf[F_TPM+tid]); }
  double s_ia=blk_red(ia,sd,tid), s_ib=blk_red(ib,sd,tid);
  double s_va=blk_red(va,sd,tid), s_vb=blk_red(vb,sd,tid);
  if(tid==0){
    double init_term = -0.5*s_ia + s_va + wsd[WSD_LOGC0];
    double mix_init  = -0.5*s_ib + s_vb + wsd[WSD_MIXC];
    double trans_term = trns + (double)NN*(-0.5*wsd[WSD_BTLAMB] + 0.5*wsd[WSD_LDLAM] - 0.5*Dd*LOG2PI_);
    double mix_trans  = mixt - 0.5*(double)NN*(double)Dd*LOG2PI_;
    double lds_kl = (init_term+trans_term) + recog - wsd[WSD_LOGZQ] - (mix_init+mix_trans);
    out[O_KL] = (float)(lds_kl + hmmkl);
  }
}

// ---------------- launch ----------------
extern "C" void kernel_launch(void* const* d_in, const int* in_sizes, int n_in,
                              void* d_out, int out_size, void* d_ws, size_t ws_size,
                              hipStream_t stream){
  const float* rJ  =(const float*)d_in[0];
  const float* rh  =(const float*)d_in[1];
  const float* loc =(const float*)d_in[2];
  const float* Tp  =(const float*)d_in[3];
  const float* Lp  =(const float*)d_in[4];
  const float* X   =(const float*)d_in[5];
  const float* il  =(const float*)d_in[6];
  const float* tl  =(const float*)d_in[7];
  const float* plam=(const float*)d_in[8];
  const float* pX  =(const float*)d_in[9];
  const float* ptau=(const float*)d_in[10];
  const float* pmu =(const float*)d_in[11];
  const float* ilp =(const float*)d_in[12];
  const float* tlp =(const float*)d_in[13];
  const int*   seed=(const int*)d_in[14];
  float* out=(float*)d_out;
  double* wsd=(double*)d_ws;
  float* wsf=(float*)((char*)d_ws + 32768);

  k_setup<<<19,256,0,stream>>>(rJ,rh,loc,Tp,Lp,X,plam,pX,ptau,pmu,wsf,wsd);
  k_eps<<<1024,256,0,stream>>>(seed, out + O_Z);
  k_hmmpow<<<1,256,0,stream>>>(tl, wsf);
  k_hmmab<<<32,256,0,stream>>>(il, wsf);
  k_cat<<<128,256,0,stream>>>(tl, wsf, out);
  // filter scan (chunked radix-8, fused point in prop)
  kf_agg<<<1024,256,0,stream>>>(rJ, rh, wsf, wsd, out);
  kf_seq<<<128,256,0,stream>>>(out, SAGG0, SSUP0);
  kf_seq<<<16,256,0,stream>>>(out, SSUP0, SHYP0);
  kf_sqx<<<1,256,0,stream>>>(out, SHYP0, 16);
  kf_sqp<<<16,256,0,stream>>>(out, SHYP0, SSUP0);
  kf_sqp<<<128,256,0,stream>>>(out, SSUP0, SAGG0);
  kf_prop<<<1024,256,0,stream>>>(rJ, rh, wsf, wsd, out);
  // affine scan (smoother + sampler), fused apply in prop
  ka_agg<<<1024,256,0,stream>>>(wsf, out);
  ka_seq<<<128,256,0,stream>>>(out, SAGG0, SSUP0);
  ka_seq<<<16,256,0,stream>>>(out, SSUP0, SHYP0);
  ka_sqx<<<1,256,0,stream>>>(out, SHYP0, 16);
  ka_sqp<<<16,256,0,stream>>>(out, SHYP0, SSUP0);
  ka_sqp<<<128,256,0,stream>>>(out, SSUP0, SAGG0);
  ka_prop<<<1024,256,0,stream>>>(wsf, out);
  k_cross<<<NN,256,0,stream>>>(wsf, out);
  k_terms<<<1024,256,0,stream>>>(rJ, rh, plam, wsf, wsd, out);
  k_final<<<1,256,0,stream>>>(il, tl, ilp, tlp, ptau, wsf, wsd, out);
}

// Round 9
// 1773.250 us; speedup vs baseline: 1.6465x; 1.6465x over previous
//
#include <hip/hip_runtime.h>
#include <math.h>
#include <stdint.h>

#define Dd 32
#define TT 8192
#define NN 8191
#define KK 16
#define LOG2PI_ 1.8378770664093453

// ---------------- ws doubles ----------------
#define WSD_LOGC0  0
#define WSD_LOGZQ  1
#define WSD_MIXC   3
#define WSD_LDLAM  4
#define WSD_BTLAMB 5
#define WSD_PR     8
#define WSD_PT     1032
#define WSD_PM     2056
// ---------------- ws floats (base = byte 32768) ----------------
#define F_TAU      0
#define F_TAUMU    1024
#define F_LAM      1056
#define F_A        2080
#define F_B        3104
#define F_ATLAM    3136
#define F_ATLAMA   4160
#define F_LAMA     5184
#define F_LAMB     6208
#define F_ATLAMB   6240
#define F_SC       6272
#define F_LAMAK    6304
#define F_ATLAMAK  22688
#define F_LAMBK    39072
#define F_ATLAMBK  39584
#define F_BTLAMBK  40096
#define F_LOGDETK  40112
#define F_TPM      40128
#define F_J0       40160
#define F_H0       41184
#define F_MLAST    41216
#define F_COVT     41248
#define F_XT       42272
#define F_TPOW     42304
#define F_ALPHA    45632
#define F_BETA     176704
#define F_EZ       307776
#define F_SCAN     340544

// scan slot layout (stride 2148 floats)
#define SSTR   2148
#define POFF   0
#define QOFF   528
#define ROFF   1056
#define PPOFF  2080
#define QQOFF  2112
#define GAMOFF 2144
#define FLGOFF 2146
// affine leaf/composite layout
#define BG     0
#define BCZ    1024
#define BCM    1056
#define BP     1088

// out offsets (floats)
#define O_Z     ((size_t)0)
#define O_EX    ((size_t)262144)
#define O_EXXT  ((size_t)524288)
#define O_CROSS ((size_t)8912896)
#define O_CAT   ((size_t)17300480)
#define O_KL    ((size_t)17431536)

// KS scratch in dead EXXT zone (plain stride-2176 slots)
#define XSLOT  2176
#define SAGG0  0

// ---------------- threefry ----------------
__device__ __forceinline__ uint32_t rotl32(uint32_t v, int d){ return (v<<d)|(v>>(32-d)); }
__device__ __forceinline__ void threefry2x32(uint32_t k0, uint32_t k1, uint32_t x0, uint32_t x1,
                                             uint32_t& o0, uint32_t& o1){
  uint32_t ks2 = k0 ^ k1 ^ 0x1BD11BDAu;
  x0 += k0; x1 += k1;
  x0+=x1; x1=rotl32(x1,13); x1^=x0;  x0+=x1; x1=rotl32(x1,15); x1^=x0;
  x0+=x1; x1=rotl32(x1,26); x1^=x0;  x0+=x1; x1=rotl32(x1, 6); x1^=x0;
  x0+=k1; x1+=ks2+1u;
  x0+=x1; x1=rotl32(x1,17); x1^=x0;  x0+=x1; x1=rotl32(x1,29); x1^=x0;
  x0+=x1; x1=rotl32(x1,16); x1^=x0;  x0+=x1; x1=rotl32(x1,24); x1^=x0;
  x0+=ks2; x1+=k0+2u;
  x0+=x1; x1=rotl32(x1,13); x1^=x0;  x0+=x1; x1=rotl32(x1,15); x1^=x0;
  x0+=x1; x1=rotl32(x1,26); x1^=x0;  x0+=x1; x1=rotl32(x1, 6); x1^=x0;
  x0+=k0; x1+=k1+3u;
  x0+=x1; x1=rotl32(x1,17); x1^=x0;  x0+=x1; x1=rotl32(x1,29); x1^=x0;
  x0+=x1; x1=rotl32(x1,16); x1^=x0;  x0+=x1; x1=rotl32(x1,24); x1^=x0;
  x0+=k1; x1+=ks2+4u;
  x0+=x1; x1=rotl32(x1,13); x1^=x0;  x0+=x1; x1=rotl32(x1,15); x1^=x0;
  x0+=x1; x1=rotl32(x1,26); x1^=x0;  x0+=x1; x1=rotl32(x1, 6); x1^=x0;
  x0+=ks2; x1+=k0+5u;
  o0=x0; o1=x1;
}
__device__ __forceinline__ float tf_normal(uint32_t bits){
  float fl = __uint_as_float((bits>>9) | 0x3F800000u) - 1.0f;
  const float lo = -0.99999994f;
  float u = fmaxf(lo, fl*2.0f + lo);
  float w = -log1pf(-u*u);
  float p;
  if (w < 5.0f){
    w -= 2.5f;
    p = 2.81022636e-08f;
    p = fmaf(p,w,3.43273939e-07f); p = fmaf(p,w,-3.5233877e-06f);
    p = fmaf(p,w,-4.39150654e-06f); p = fmaf(p,w,0.00021858087f);
    p = fmaf(p,w,-0.00125372503f); p = fmaf(p,w,-0.00417768164f);
    p = fmaf(p,w,0.246640727f); p = fmaf(p,w,1.50140941f);
  } else {
    w = sqrtf(w) - 3.0f;
    p = -0.000200214257f;
    p = fmaf(p,w,0.000100950558f); p = fmaf(p,w,0.00134934322f);
    p = fmaf(p,w,-0.00367342844f); p = fmaf(p,w,0.00573950773f);
    p = fmaf(p,w,-0.0076224613f); p = fmaf(p,w,0.00943887047f);
    p = fmaf(p,w,1.00167406f); p = fmaf(p,w,2.83297682f);
  }
  return 1.4142135381698608f * (p*u);
}

// ---------------- helpers ----------------
__device__ __forceinline__ void tri_rc(int i, int& r, int& c){
  int rr = (int)((sqrtf(8.f*(float)i+1.f)-1.f)*0.5f);
  while((rr+1)*(rr+2)/2 <= i) ++rr;
  while(rr*(rr+1)/2 > i) --rr;
  r = rr; c = i - rr*(rr+1)/2;
}

__device__ __forceinline__ float dot36(const float* A, int r, const float* B, int c){
  const float4* a4 = (const float4*)(A + r*36);
  const float4* b4 = (const float4*)(B + c*36);
  float sx=0.f, sy=0.f, sz=0.f, sw=0.f;
  #pragma unroll
  for(int m=0;m<8;++m){
    float4 a=a4[m], b=b4[m];
    sx=fmaf(a.x,b.x,sx); sy=fmaf(a.y,b.y,sy);
    sz=fmaf(a.z,b.z,sz); sw=fmaf(a.w,b.w,sw);
  }
  return (sx+sy)+(sz+sw);
}
__device__ __forceinline__ void t36_rows(float* dst, const float* src, int tid){
  int r=tid>>3, c0=(tid&7)<<2;
  *(float4*)(dst + r*36 + c0) = *(const float4*)(src + r*32 + c0);
}
__device__ __forceinline__ void t36_tr(float* dst, const float* src, int tid){
  int m=tid>>3, j0=(tid&7)<<2;
  float4 v = *(const float4*)(src + m*32 + j0);
  dst[(j0+0)*36+m]=v.x; dst[(j0+1)*36+m]=v.y;
  dst[(j0+2)*36+m]=v.z; dst[(j0+3)*36+m]=v.w;
}
__device__ __forceinline__ void t36_tr36(float* dst, const float* src, int tid){
  int m=tid>>3, j0=(tid&7)<<2;
  float4 v = *(const float4*)(src + m*36 + j0);
  dst[(j0+0)*36+m]=v.x; dst[(j0+1)*36+m]=v.y;
  dst[(j0+2)*36+m]=v.z; dst[(j0+3)*36+m]=v.w;
}
__device__ __forceinline__ void t36_sym(float* dst, const float* packed, int tid){
  for(int q=tid;q<528;q+=256){
    int r,c; tri_rc(q,r,c);
    float v=packed[q];
    dst[r*36+c]=v; dst[c*36+r]=v;
  }
}

// slot IO: full 2148-float slots (wsf scan slots)
__device__ __forceinline__ void ld_slot(float* dst, const float* src, int tid){
  #pragma unroll 3
  for(int q=tid;q<537;q+=256) ((float4*)dst)[q] = ((const float4*)src)[q];
}
// scratch pseudo-slot p stored in tails (floats 560..1023) of O_CROSS slots 5p..5p+4
__device__ __forceinline__ void st_pref(float* cb, int p, const float* C, int tid){
  #pragma unroll 3
  for(int q=tid;q<537;q+=256){
    int w=q/116, o=(q-116*w)<<2;
    *(float4*)(cb + (((size_t)(5*p+w))<<10) + 560 + o) = ((const float4*)C)[q];
  }
}
__device__ __forceinline__ void ld_pref(float* C, const float* cb, int p, int tid){
  #pragma unroll 3
  for(int q=tid;q<537;q+=256){
    int w=q/116, o=(q-116*w)<<2;
    ((float4*)C)[q] = *(const float4*)(cb + (((size_t)(5*p+w))<<10) + 560 + o);
  }
}
// KS scratch IO: plain stride-XSLOT slots at absolute float base
__device__ __forceinline__ void ld_x(float* C, const float* out, unsigned long long base, int i, int tid){
  const float4* src = (const float4*)(out + base + (size_t)i*XSLOT);
  #pragma unroll 3
  for(int q=tid;q<537;q+=256) ((float4*)C)[q] = src[q];
}
__device__ __forceinline__ void st_x(float* out, unsigned long long base, int i, const float* C, int tid){
  float4* dst = (float4*)(out + base + (size_t)i*XSLOT);
  #pragma unroll 3
  for(int q=tid;q<537;q+=256) dst[q] = ((const float4*)C)[q];
}

// Fused cholesky + L^-1, quad-vectorized, stride 36.
__device__ double chol_linv36(float* W, float* Li, float* rdg, int tid){
  int r = tid>>3, c0 = (tid&7)<<2;
  {
    float4 z = make_float4(0.f,0.f,0.f,0.f);
    if(r>=c0 && r<c0+4) ((float*)&z)[r-c0]=1.f;
    *(float4*)(Li + r*36 + c0) = z;
  }
  double slog=0.0;
  for(int j=0;j<33;++j){
    if(j<32){
      float dd = W[j*36+j];
      float rd = 1.0f/sqrtf(dd);
      float invd = rd*rd;
      if(tid==0){ rdg[j]=rd; slog += (double)(0.5f*__logf(dd)); }
      if(r>j && c0+3>=j){
        float t0 = W[j*36+r]*invd;
        float4 wj  = *(const float4*)(W+j*36+c0);
        float4 cur = *(float4*)(W+r*36+c0);
        float rdl = rd;
        int c;
        c=c0;   cur.x = (c>j)? fmaf(-t0, wj.x, cur.x) : ((c==j)? cur.x*rdl : cur.x);
        c=c0+1; cur.y = (c>j)? fmaf(-t0, wj.y, cur.y) : ((c==j)? cur.y*rdl : cur.y);
        c=c0+2; cur.z = (c>j)? fmaf(-t0, wj.z, cur.z) : ((c==j)? cur.z*rdl : cur.z);
        c=c0+3; cur.w = (c>j)? fmaf(-t0, wj.w, cur.w) : ((c==j)? cur.w*rdl : cur.w);
        *(float4*)(W+r*36+c0) = cur;
      }
    }
    if(j>0){
      int ii=j-1;
      if(r>ii && c0<=ii){
        float wri = W[r*36+ii]*rdg[ii];
        float4 lrow = *(const float4*)(Li+ii*36+c0);
        float4 cur  = *(float4*)(Li+r*36+c0);
        if(c0+0<=ii) cur.x = fmaf(-wri, lrow.x, cur.x);
        if(c0+1<=ii) cur.y = fmaf(-wri, lrow.y, cur.y);
        if(c0+2<=ii) cur.z = fmaf(-wri, lrow.z, cur.z);
        if(c0+3<=ii) cur.w = fmaf(-wri, lrow.w, cur.w);
        *(float4*)(Li+r*36+c0) = cur;
      }
    }
    __syncthreads();
  }
  {
    float rr = rdg[r];
    float4 cur = *(float4*)(Li+r*36+c0);
    cur.x*=rr; cur.y*=rr; cur.z*=rr; cur.w*=rr;
    *(float4*)(Li+r*36+c0) = cur;
  }
  __syncthreads();
  return slog;
}

__device__ __forceinline__ double blk_red(double v, double* sd, int tid){
  sd[tid]=v; __syncthreads();
  for(int s=128;s>0;s>>=1){ if(tid<s) sd[tid]+=sd[tid+s]; __syncthreads(); }
  double r=sd[0]; __syncthreads(); return r;
}
__device__ double blk_logdet(float* Ms, int tid){
  double sl = 0.0;
  for (int j=0;j<Dd;++j){
    float dd = Ms[j*33+j];
    sl += log((double)dd);
    float invd = 1.0f/dd;
    #pragma unroll
    for(int p=0;p<4;p++){
      int cell = tid + (p<<8); int r=cell>>5, c=cell&31;
      if(r>j && c>j && c<=r) Ms[r*33+c] -= Ms[r*33+j]*(Ms[c*33+j]*invd);
    }
    __syncthreads();
  }
  return sl;
}

// ---------- filter-scan device pieces ----------
__device__ void unary_f(float* C, const float* wsf, const double* wsd, int tid){
  __syncthreads();
  #pragma unroll 3
  for(int q=tid;q<528;q+=256){
    int r,c; tri_rc(q,r,c);
    C[POFF+q]=0.f;
    C[QOFF+q]=wsf[F_J0 + r*32+c];
  }
  #pragma unroll 4
  for(int q=tid;q<1024;q+=256) C[ROFF+q]=0.f;
  if(tid<32){ C[PPOFF+tid]=0.f; C[QQOFF+tid]=wsf[F_H0+tid]; }
  if(tid==0){ *(double*)(C+GAMOFF)=wsd[WSD_LOGC0]; C[FLGOFF]=1.f; }
}
__device__ void leaf_f(float* C, int t, const float* rJ, const float* rh,
                       const float* wsf, const double* wsd, int tid){
  __syncthreads();
  #pragma unroll 3
  for(int q=tid;q<528;q+=256){
    int r,c; tri_rc(q,r,c);
    C[POFF+q] = wsf[F_ATLAMA + r*32+c] + ((r==c)?1e-6f:0.f);
    C[QOFF+q] = wsf[F_LAM + r*32+c] + rJ[(size_t)t*1024 + r*32+c];
  }
  #pragma unroll 4
  for(int q=tid;q<1024;q+=256) C[ROFF+q] = -wsf[F_ATLAM+q];
  if(tid<32){
    C[PPOFF+tid] = -wsf[F_ATLAMB+tid];
    C[QQOFF+tid] = wsf[F_LAMB+tid] + rh[(size_t)t*32+tid];
  }
  if(tid==0){
    *(double*)(C+GAMOFF) = -0.5*wsd[WSD_BTLAMB] + 0.5*wsd[WSD_LDLAM];
    C[FLGOFF]=1.f;
  }
}

// general filter combine, in-place on C (LDS); Y in LDS. C earlier, Y later.
__device__ void comb_f(float* C, const float* Y, float* W, float* Li, float* BA, float* BB,
                       float* rdg, float* Ls, int tid){
  __syncthreads();
  int fc=(C[FLGOFF]!=0.f), fy=(Y[FLGOFF]!=0.f);
  if(fy && !fc){
    #pragma unroll 3
    for(int q=tid;q<537;q+=256) ((float4*)C)[q]=((const float4*)Y)[q];
  } else if(fy){
    #pragma unroll 3
    for(int q=tid;q<528;q+=256){
      int r,c; tri_rc(q,r,c);
      float w = C[QOFF+q] + Y[POFF+q];
      W[r*36+c]=w; W[c*36+r]=w;
    }
    t36_rows(BA, C+ROFF, tid);
    t36_tr  (BB, Y+ROFF, tid);
    __syncthreads();
    double slog = chol_linv36(W, Li, rdg, tid);
    if(tid<32){
      float acc=0.f;
      for(int m=0;m<=tid;++m) acc=fmaf(Li[tid*36+m], C[QQOFF+m]+Y[PPOFF+m], acc);
      Ls[tid]=acc;
    }
    #pragma unroll 4
    for(int q=tid;q<1024;q+=256){ int i2=q>>5, j=q&31; W[j*36+i2]=dot36(Li,i2,BA,j); }  // T1t
    __syncthreads();
    #pragma unroll 4
    for(int q=tid;q<1024;q+=256){ int i2=q>>5, j=q&31; BA[j*36+i2]=dot36(Li,i2,BB,j); } // T2t
    __syncthreads();
    #pragma unroll 3
    for(int q=tid;q<528;q+=256){
      int r,c; tri_rc(q,r,c);
      C[POFF+q] = C[POFF+q] - dot36(W,r,W,c);
      C[QOFF+q] = Y[QOFF+q] - dot36(BA,r,BA,c);
    }
    #pragma unroll 4
    for(int q=tid;q<1024;q+=256){ int r=q>>5,c=q&31; C[ROFF+q] = -dot36(W,r,BA,c); }
    if(tid<32){
      float ap=0.f,aq=0.f;
      #pragma unroll
      for(int m=0;m<32;++m){ ap=fmaf(W[tid*36+m],Ls[m],ap); aq=fmaf(BA[tid*36+m],Ls[m],aq); }
      C[PPOFF+tid] -= ap;
      C[QQOFF+tid] = Y[QQOFF+tid] - aq;
    }
    if(tid==0){
      double g = *(double*)(C+GAMOFF) + *(const double*)(Y+GAMOFF);
      double dot=0.0;
      for(int m=0;m<32;++m) dot += (double)Ls[m]*(double)Ls[m];
      *(double*)(C+GAMOFF) = g + 0.5*dot - slog;
    }
  }
  __syncthreads();
}

// specialized advance with leaf t (shares chol with optional point output for t-1)
template<int POINT>
__device__ void adv_leaf_f(float* C, int t, const float* rJ, const float* rh,
                           const float* wsf, const double* wsd,
                           const float* CLAMA, const float* CATA, const float* catb,
                           float* W, float* Li, float* BA, float* BB,
                           float* rdg, float* Lu, float* uv, float* ev,
                           float* pe, float* outc, const float* outz, int tid){
  __syncthreads();
  #pragma unroll 3
  for(int q=tid;q<528;q+=256){
    int r,c; tri_rc(q,r,c);
    float w = C[QOFF+q] + CATA[r*36+c];
    W[r*36+c]=w; W[c*36+r]=w;
  }
  t36_rows(BB, C+ROFF, tid);
  if(tid<32){
    uv[tid] = C[QQOFF+tid] - catb[tid];
    if(POINT) ev[tid] = outz[(size_t)(t-1)*32+tid];
  }
  __syncthreads();
  double slog = chol_linv36(W, Li, rdg, tid);
  if(tid<32){
    float acc=0.f;
    for(int m=0;m<=tid;++m) acc=fmaf(Li[tid*36+m], uv[m], acc);
    Lu[tid]=acc;
  }
  #pragma unroll 4
  for(int q=tid;q<1024;q+=256){ int i2=q>>5, j=q&31; W[j*36+i2]=dot36(Li,i2,BB,j); }    // T1t
  __syncthreads();
  #pragma unroll 4
  for(int q=tid;q<1024;q+=256){ int i2=q>>5, j=q&31; BA[j*36+i2]=dot36(Li,i2,CLAMA,j); } // TA
  __syncthreads();
  if(POINT){
    t36_tr36(BB, Li, tid);    // BB = LiT rows
    __syncthreads();
    #pragma unroll 4
    for(int q=tid;q<1024;q+=256){ int r=q>>5,c=q&31; pe[BG+q]=dot36(BB,r,BA,c); }
    #pragma unroll 3
    for(int q=tid;q<528;q+=256){ int r,c; tri_rc(q,r,c); float a=dot36(BB,r,BB,c); pe[BP+q]=a; outc[q]=a; }
    if(tid<32){
      float ag=0.f, ay=0.f;
      for(int m2=tid;m2<32;++m2){ float lv=Li[m2*36+tid]; ag=fmaf(lv,Lu[m2],ag); ay=fmaf(lv,ev[m2],ay); }
      pe[BCM+tid]=ag; pe[BCZ+tid]=ag+ay; outc[528+tid]=ag;
    }
    if(tid==0) pe[FLGOFF]=1.f;
  }
  // advance writes (in-place on C)
  #pragma unroll 3
  for(int q=tid;q<528;q+=256){
    int r,c; tri_rc(q,r,c);
    C[POFF+q] = C[POFF+q] - dot36(W,r,W,c);
    C[QOFF+q] = (wsf[F_LAM + r*32+c] + rJ[(size_t)t*1024 + r*32+c]) - dot36(BA,r,BA,c);
  }
  #pragma unroll 4
  for(int q=tid;q<1024;q+=256){ int r=q>>5,c=q&31; C[ROFF+q] = dot36(W,r,BA,c); }
  if(tid<32){
    float ap=0.f,aq=0.f;
    #pragma unroll
    for(int m=0;m<32;++m){ ap=fmaf(W[tid*36+m],Lu[m],ap); aq=fmaf(BA[tid*36+m],Lu[m],aq); }
    C[PPOFF+tid] -= ap;
    C[QQOFF+tid] = (wsf[F_LAMB+tid] + rh[(size_t)t*32+tid]) + aq;
  }
  if(tid==0){
    double dot=0.0;
    for(int m=0;m<32;++m) dot += (double)Lu[m]*(double)Lu[m];
    *(double*)(C+GAMOFF) += (-0.5*wsd[WSD_BTLAMB] + 0.5*wsd[WSD_LDLAM]) + 0.5*dot - slog;
  }
}

// final-state from total C (block 1023 of kf_prop)
__device__ void final_f(float* C, float* W, float* Li, float* BB,
                        float* rdg, float* Lu, float* uv, float* ev, float* gv,
                        float* wsf, double* wsd, float* out, int tid){
  __syncthreads();
  #pragma unroll 3
  for(int q=tid;q<528;q+=256){
    int r,c; tri_rc(q,r,c);
    float w = C[QOFF+q] + ((r==c)?1e-6f:0.f);
    W[r*36+c]=w; W[c*36+r]=w;
  }
  if(tid<32){ uv[tid]=C[QQOFF+tid]; ev[tid]=out[O_Z+(size_t)NN*32+tid]; }
  __syncthreads();
  double slog2 = chol_linv36(W, Li, rdg, tid);
  if(tid<32){
    float acc=0.f;
    for(int m=0;m<=tid;++m) acc=fmaf(Li[tid*36+m], uv[m], acc);
    Lu[tid]=acc;
  }
  t36_tr36(BB, Li, tid);
  __syncthreads();
  if(tid<32){
    float am=0.f, ay=0.f;
    for(int m2=tid;m2<32;++m2){ float lv=Li[m2*36+tid]; am=fmaf(lv,Lu[m2],am); ay=fmaf(lv,ev[m2],ay); }
    gv[tid]=am;
    wsf[F_MLAST+tid]=am; out[O_EX+(size_t)NN*32+tid]=am;
    float xt=am+ay;
    wsf[F_XT+tid]=xt; out[O_Z+(size_t)NN*32+tid]=xt;
  }
  __syncthreads();
  #pragma unroll 4
  for(int q=tid;q<1024;q+=256){
    int r=q>>5,c=q&31;
    float a = dot36(BB,r,BB,c);
    wsf[F_COVT+q]=a;
    out[O_EXXT+(size_t)NN*1024+q]=a+gv[r]*gv[c];
  }
  if(tid==0){
    double gam=*(double*)(C+GAMOFF);
    double hm=0.0;
    for(int m=0;m<32;++m) hm += (double)uv[m]*(double)gv[m];
    wsd[WSD_LOGZQ] = gam + 0.5*hm + 0.5*Dd*LOG2PI_ - slog2;
  }
}

// ---------- affine-scan device pieces ----------
// general affine combine, in-place on C; result = Y∘X (C earlier, Y later)
__device__ void comb_a(float* C, const float* Y, float* B1, float* B2, float* B3, float* B4,
                       float* vcz, float* vcm, int tid){
  __syncthreads();
  int fc=(C[FLGOFF]!=0.f), fy=(Y[FLGOFF]!=0.f);
  if(fy && !fc){
    #pragma unroll 3
    for(int q=tid;q<537;q+=256) ((float4*)C)[q]=((const float4*)Y)[q];
  } else if(fy){
    t36_rows(B1, Y+BG, tid);
    t36_tr  (B3, C+BG, tid);
    t36_sym (B4, C+BP, tid);
    if(tid<32){ vcz[tid]=C[BCZ+tid]; vcm[tid]=C[BCM+tid]; }
    __syncthreads();
    #pragma unroll 4
    for(int q=tid;q<1024;q+=256){ int r=q>>5,c=q&31; C[BG+q]=dot36(B1,r,B3,c); }
    #pragma unroll 4
    for(int q=tid;q<1024;q+=256){ int r=q>>5,c=q&31; B2[r*36+c]=dot36(B1,r,B4,c); }
    __syncthreads();
    #pragma unroll 3
    for(int q=tid;q<528;q+=256){ int r,c; tri_rc(q,r,c); C[BP+q]=dot36(B2,r,B1,c)+Y[BP+q]; }
    if(tid<32){
      float az=0.f,am=0.f;
      #pragma unroll
      for(int m=0;m<32;++m){ float g=B1[tid*36+m]; az=fmaf(g,vcz[m],az); am=fmaf(g,vcm[m],am); }
      C[BCZ+tid]=az+Y[BCZ+tid];
      C[BCM+tid]=am+Y[BCM+tid];
    }
  }
  __syncthreads();
}

// ---------------- setup: 19 independent blocks ----------------
__global__ __launch_bounds__(256) void k_setup(const float* rJ, const float* rh, const float* loc,
    const float* Tp, const float* Lp, const float* X, const float* plam, const float* pX,
    const float* ptau, const float* pmu, float* wsf, double* wsd){
  __shared__ float s1[1056], s2[1056], s3[1056];
  __shared__ float sv[32], sv2[32];
  int tid=threadIdx.x; int b=blockIdx.x;
  if(b==0){
    for(int p=0;p<4;p++){int cell=tid+(p<<8);int r=cell>>5,c=cell&31; s1[r*33+c]=Tp[cell];}
    if(tid<32) sv[tid]=loc[tid];
    __syncthreads();
    for(int p=0;p<4;p++){int cell=tid+(p<<8);int r=cell>>5,c=cell&31;
      float a=0.f;
      #pragma unroll
      for(int m=0;m<Dd;++m) a=fmaf(s1[r*33+m], s1[c*33+m], a);
      if(r==c) a+=1e-8f;
      s2[r*33+c]=a; wsf[F_TAU+cell]=a; wsf[F_J0+cell]=a+rJ[cell];
    }
    __syncthreads();
    if(tid<32){ float tm=0.f;
      #pragma unroll
      for(int m=0;m<Dd;++m) tm=fmaf(s2[tid*33+m], sv[m], tm);
      sv2[tid]=tm; wsf[F_TAUMU+tid]=tm; wsf[F_H0+tid]=tm+rh[tid];
    }
    __syncthreads();
    double ldt = blk_logdet(s2, tid);
    if(tid==0){ double dd=0; for(int m=0;m<Dd;++m) dd += (double)sv[m]*(double)sv2[m];
      wsd[WSD_LOGC0] = -0.5*dd + 0.5*ldt - 0.5*Dd*LOG2PI_; }
  } else if(b==1){
    for(int p=0;p<4;p++){int cell=tid+(p<<8);int r=cell>>5,c=cell&31; s1[r*33+c]=Lp[cell];}
    __syncthreads();
    for(int p=0;p<4;p++){int cell=tid+(p<<8);int r=cell>>5,c=cell&31;
      float a=0.f;
      #pragma unroll
      for(int m=0;m<Dd;++m) a=fmaf(s1[r*33+m], s1[c*33+m], a);
      if(r==c) a+=1e-8f;
      s2[r*33+c]=a; wsf[F_LAM+cell]=a;
    }
    __syncthreads();
    for(int p=0;p<4;p++){int cell=tid+(p<<8);int r=cell>>5,c=cell&31;
      float a=X[r*33+c]; s3[r*33+c]=a; wsf[F_A+cell]=a; }
    if(tid<32){ sv[tid]=X[tid*33+32]; wsf[F_B+tid]=sv[tid]; }
    __syncthreads();
    for(int p=0;p<4;p++){int cell=tid+(p<<8);int r=cell>>5,c=cell&31;
      float a=0.f,b2=0.f;
      #pragma unroll
      for(int m=0;m<Dd;++m){ a=fmaf(s2[r*33+m], s3[m*33+c], a); b2=fmaf(s3[m*33+r], s2[m*33+c], b2); }
      s1[r*33+c]=a; wsf[F_LAMA+cell]=a; wsf[F_ATLAM+cell]=b2;
    }
    if(tid<32){ float lb=0.f;
      #pragma unroll
      for(int m=0;m<Dd;++m) lb=fmaf(s2[tid*33+m], sv[m], lb);
      sv2[tid]=lb; wsf[F_LAMB+tid]=lb;
    }
    __syncthreads();
    for(int p=0;p<4;p++){int cell=tid+(p<<8);int r=cell>>5,c=cell&31;
      float a=0.f;
      #pragma unroll
      for(int m=0;m<Dd;++m) a=fmaf(s3[m*33+r], s1[m*33+c], a);
      wsf[F_ATLAMA+cell]=a;
    }
    if(tid<32){ float ab=0.f;
      #pragma unroll
      for(int m=0;m<Dd;++m) ab=fmaf(s3[m*33+tid], sv2[m], ab);
      wsf[F_ATLAMB+tid]=ab;
    }
    if(tid==0){ double bb=0; for(int m=0;m<Dd;++m) bb += (double)sv[m]*(double)sv2[m];
      wsd[WSD_BTLAMB]=bb; }
    __syncthreads();
    double ldl = blk_logdet(s2, tid);
    if(tid==0) wsd[WSD_LDLAM]=ldl;
  } else if(b==2){
    for(int p=0;p<4;p++){int cell=tid+(p<<8);int r=cell>>5,c=cell&31; s1[r*33+c]=ptau[cell];}
    if(tid<32) sv[tid]=pmu[tid];
    __syncthreads();
    if(tid<32){ float tm=0.f;
      #pragma unroll
      for(int m=0;m<Dd;++m) tm=fmaf(s1[tid*33+m], sv[m], tm);
      sv2[tid]=tm; wsf[F_TPM+tid]=tm;
    }
    __syncthreads();
    double ldp = blk_logdet(s1, tid);
    if(tid==0){ double dd=0; for(int m=0;m<Dd;++m) dd += (double)sv[m]*(double)sv2[m];
      wsd[WSD_MIXC] = -0.5*dd + 0.5*ldp - 0.5*Dd*LOG2PI_; }
  } else {
    int k2 = b-3;
    for(int p=0;p<4;p++){int cell=tid+(p<<8);int r=cell>>5,c=cell&31;
      s2[r*33+c]=plam[k2*1024+cell]; s3[r*33+c]=pX[k2*1056 + r*33 + c];}
    if(tid<32) sv[tid]=pX[k2*1056 + tid*33 + 32];
    __syncthreads();
    for(int p=0;p<4;p++){int cell=tid+(p<<8);int r=cell>>5,c=cell&31;
      float a=0.f;
      #pragma unroll
      for(int m=0;m<Dd;++m) a=fmaf(s2[r*33+m], s3[m*33+c], a);
      s1[r*33+c]=a; wsf[F_LAMAK + (size_t)k2*1024 + cell]=a;
    }
    if(tid<32){ float lb=0.f;
      #pragma unroll
      for(int m=0;m<Dd;++m) lb=fmaf(s2[tid*33+m], sv[m], lb);
      sv2[tid]=lb; wsf[F_LAMBK + k2*32 + tid]=lb;
    }
    __syncthreads();
    for(int p=0;p<4;p++){int cell=tid+(p<<8);int r=cell>>5,c=cell&31;
      float a=0.f;
      #pragma unroll
      for(int m=0;m<Dd;++m) a=fmaf(s3[m*33+r], s1[m*33+c], a);
      wsf[F_ATLAMAK + (size_t)k2*1024 + cell]=a;
    }
    if(tid<32){ float ab=0.f;
      #pragma unroll
      for(int m=0;m<Dd;++m) ab=fmaf(s3[m*33+tid], sv2[m], ab);
      wsf[F_ATLAMBK + k2*32 + tid]=ab;
    }
    if(tid==0){ float bb=0.f; for(int m=0;m<Dd;++m) bb=fmaf(sv[m],sv2[m],bb);
      wsf[F_BTLAMBK + k2]=bb; }
    __syncthreads();
    double dk = blk_logdet(s2, tid);
    if(tid==0) wsf[F_LOGDETK + k2]=(float)dk;
  }
}

// ---------------- eps ----------------
__global__ __launch_bounds__(256) void k_eps(const int* seedp, float* outz){
  uint32_t seed = (uint32_t)seedp[0];
  uint32_t K0,K1;
  threefry2x32(0u, seed, 0u, 1u, K0, K1);
  uint32_t i = blockIdx.x*256u + threadIdx.x;
  uint32_t o0,o1;
  threefry2x32(K0, K1, 0u, i, o0, o1);
  outz[i] = tf_normal(o0 ^ o1);
}

// ---------------- HMM ----------------
__global__ __launch_bounds__(256) void k_hmmpow(const float* tl, float* wsf){
  __shared__ float A0[256], A1[256];
  int tid=threadIdx.x;
  A0[tid]=tl[tid];
  wsf[F_TPOW+tid]=A0[tid];
  __syncthreads();
  float* cur=A0; float* nxt=A1;
  for(int k=1;k<13;++k){
    int i=tid>>4, j=tid&15;
    float mx=-3.0e38f;
    #pragma unroll
    for(int m=0;m<16;++m) mx=fmaxf(mx, cur[i*16+m]+cur[m*16+j]);
    float s=0.f;
    #pragma unroll
    for(int m=0;m<16;++m) s+=__expf(cur[i*16+m]+cur[m*16+j]-mx);
    float v=mx+__logf(s);
    nxt[tid]=v; wsf[F_TPOW+k*256+tid]=v;
    __syncthreads();
    float* t2=cur; cur=nxt; nxt=t2;
  }
}

__global__ __launch_bounds__(256) void k_hmmab(const float* il, float* wsf){
  __shared__ float S[3328];
  int tid=threadIdx.x;
  for(int p=0;p<13;++p) S[p*256+tid]=wsf[F_TPOW+p*256+tid];
  __syncthreads();
  int n = blockIdx.x*256 + tid;
  if(n>NN-1) return;
  float v[16], w[16];
  #pragma unroll
  for(int j=0;j<16;++j) v[j]=il[j];
  for(int k=0;k<13;++k){
    if((n>>k)&1){
      #pragma unroll
      for(int j=0;j<16;++j){
        float mx=-3.0e38f;
        #pragma unroll
        for(int i2=0;i2<16;++i2) mx=fmaxf(mx, v[i2]+S[k*256+i2*16+j]);
        float s=0.f;
        #pragma unroll
        for(int i2=0;i2<16;++i2) s+=__expf(v[i2]+S[k*256+i2*16+j]-mx);
        w[j]=mx+__logf(s);
      }
      #pragma unroll
      for(int j=0;j<16;++j) v[j]=w[j];
    }
  }
  #pragma unroll
  for(int j=0;j<16;++j) wsf[F_ALPHA+(size_t)n*16+j]=v[j];
  if(n==NN-1){
    float mx=-3.0e38f;
    #pragma unroll
    for(int j=0;j<16;++j) mx=fmaxf(mx,v[j]);
    float s=0.f;
    #pragma unroll
    for(int j=0;j<16;++j) s+=__expf(v[j]-mx);
    wsf[F_SC+0]=mx+__logf(s);
  }
  int m = NN-1-n;
  float b[16];
  #pragma unroll
  for(int i2=0;i2<16;++i2) b[i2]=0.f;
  for(int k=0;k<13;++k){
    if((m>>k)&1){
      #pragma unroll
      for(int i2=0;i2<16;++i2){
        float mx=-3.0e38f;
        #pragma unroll
        for(int j=0;j<16;++j) mx=fmaxf(mx, S[k*256+i2*16+j]+b[j]);
        float s=0.f;
        #pragma unroll
        for(int j=0;j<16;++j) s+=__expf(S[k*256+i2*16+j]+b[j]-mx);
        w[i2]=mx+__logf(s);
      }
      #pragma unroll
      for(int i2=0;i2<16;++i2) b[i2]=w[i2];
    }
  }
  #pragma unroll
  for(int i2=0;i2<16;++i2) wsf[F_BETA+(size_t)n*16+i2]=b[i2];
}

__global__ __launch_bounds__(256) void k_cat(const float* tl, float* wsf, float* out){
  __shared__ float Ts[256]; __shared__ float al[1024]; __shared__ float be[1040];
  int tid=threadIdx.x;
  Ts[tid]=tl[tid];
  float logZ = wsf[F_SC+0];
  int n0=blockIdx.x*64;
  for(int q=tid;q<1024;q+=256){ int n=n0+(q>>4); al[q] = (n<NN)? wsf[F_ALPHA+(size_t)n*16+(q&15)] : 0.f; }
  for(int q=tid;q<1040;q+=256){ int n=n0+(q>>4); be[q] = (n<NN)? wsf[F_BETA +(size_t)n*16+(q&15)] : 0.f; }
  __syncthreads();
  for(int q=tid;q<1024;q+=256){ int n=n0+(q>>4);
    if(n<NN) out[O_CAT+(size_t)n*16+(q&15)] = __expf(al[q]+be[q]-logZ); }
  int i=tid>>4, j=tid&15;
  float acc=0.f;
  #pragma unroll 4
  for(int nn=0;nn<64;++nn){
    int n=n0+nn;
    if(n<NN-1) acc += __expf(al[nn*16+i]+Ts[i*16+j]+be[(nn+1)*16+j]-logZ);
  }
  wsf[F_EZ + blockIdx.x*256 + tid]=acc;
}

// ---------------- F1: chunk aggregates -> XB0 ----------------
__global__ __launch_bounds__(256,4) void kf_agg(const float* rJ, const float* rh,
                                                float* wsf, double* wsd, float* out,
                                                unsigned long long xb0){
  __shared__ __align__(16) float C[2148];
  __shared__ __align__(16) float W[1152], Li[1152], BA[1152], BB[1152], CLAMA[1152], CATA[1152];
  __shared__ float rdg[32], Lu[32], uv[32], ev[32], catb[32];
  int tid=threadIdx.x; int i=blockIdx.x;
  if(i==0 && tid==0) wsf[F_SCAN+FLGOFF]=0.f;   // slot 0 = affine pad (flag 0)
  t36_rows(CLAMA, wsf+F_LAMA, tid);
  for(int q=tid;q<528;q+=256){ int r,c; tri_rc(q,r,c);
    float v=wsf[F_ATLAMA+r*32+c]+((r==c)?1e-6f:0.f); CATA[r*36+c]=v; CATA[c*36+r]=v; }
  if(tid<32) catb[tid]=wsf[F_ATLAMB+tid];
  if(i==0) unary_f(C, wsf, wsd, tid);
  else     leaf_f(C, 8*i, rJ, rh, wsf, wsd, tid);
  for(int e=1;e<8;++e)
    adv_leaf_f<0>(C, 8*i+e, rJ, rh, wsf, wsd, CLAMA, CATA, catb,
                  W,Li,BA,BB, rdg,Lu,uv,ev, (float*)0, (float*)0, (const float*)0, tid);
  __syncthreads();
  st_x(out, xb0, i, C, tid);
}

// ---------------- F2: Kogge-Stone level ----------------
__global__ __launch_bounds__(256,4) void kf_ks(float* out, int d,
                                               unsigned long long sb, unsigned long long db){
  __shared__ __align__(16) float C[2148], Y[2148];
  __shared__ __align__(16) float W[1152], Li[1152], BA[1152], BB[1152];
  __shared__ float rdg[32], Ls[32];
  int tid=threadIdx.x; int i=blockIdx.x;
  if(i<d){
    const float4* s=(const float4*)(out+sb+(size_t)i*XSLOT);
    float4* dd=(float4*)(out+db+(size_t)i*XSLOT);
    #pragma unroll 3
    for(int q=tid;q<537;q+=256) dd[q]=s[q];
    return;
  }
  ld_x(C, out, sb, i-d, tid);
  ld_x(Y, out, sb, i,   tid);
  comb_f(C, Y, W,Li,BA,BB, rdg,Ls, tid);
  st_x(out, db, i, C, tid);
}

// ---------------- F3: propagate + fused point ----------------
__global__ __launch_bounds__(256,4) void kf_prop(const float* rJ, const float* rh,
                                                 float* wsf, double* wsd, float* out,
                                                 unsigned long long xb0){
  __shared__ __align__(16) float C[2148];
  __shared__ __align__(16) float W[1152], Li[1152], BA[1152], BB[1152], CLAMA[1152], CATA[1152];
  __shared__ float rdg[32], Lu[32], uv[32], ev[32], catb[32], gv[32];
  int tid=threadIdx.x; int i=blockIdx.x;
  if(i>0) ld_x(C, out, xb0, i-1, tid);    // exclusive prefix of chunk i
  t36_rows(CLAMA, wsf+F_LAMA, tid);
  for(int q=tid;q<528;q+=256){ int r,c; tri_rc(q,r,c);
    float v=wsf[F_ATLAMA+r*32+c]+((r==c)?1e-6f:0.f); CATA[r*36+c]=v; CATA[c*36+r]=v; }
  if(tid<32) catb[tid]=wsf[F_ATLAMB+tid];
  for(int e=0;e<8;++e){
    int j=8*i+e;
    if(j==0){
      unary_f(C, wsf, wsd, tid);
    } else {
      adv_leaf_f<1>(C, j, rJ, rh, wsf, wsd, CLAMA, CATA, catb,
                    W,Li,BA,BB, rdg,Lu,uv,ev,
                    wsf + F_SCAN + (size_t)j*SSTR,
                    out + O_CROSS + (size_t)(j-1)*1024,
                    out + O_Z, tid);
    }
  }
  if(i==1023) final_f(C, W,Li,BB, rdg,Lu,uv,ev,gv, wsf, wsd, out, tid);
}

// ---------------- A1: affine chunk aggregates -> XB0 ----------------
__global__ __launch_bounds__(256,4) void ka_agg(float* wsf, float* out, unsigned long long xb0){
  __shared__ __align__(16) float C[2148], Y[2148];
  __shared__ __align__(16) float B1[1152], B2[1152], B3[1152], B4[1152];
  __shared__ float vcz[32], vcm[32];
  int tid=threadIdx.x; int i=blockIdx.x;
  ld_slot(C, wsf + F_SCAN + (size_t)(NN-8*i)*SSTR, tid);
  for(int e=1;e<8;++e){
    int j=8*i+e; int s=(j<NN)? (NN-j) : 0;
    ld_slot(Y, wsf + F_SCAN + (size_t)s*SSTR, tid);
    comb_a(C, Y, B1,B2,B3,B4, vcz,vcm, tid);
  }
  __syncthreads();
  st_x(out, xb0, i, C, tid);
}

// ---------------- A2: Kogge-Stone level (last level publishes to O_CROSS tails) ----------------
template<int PUB>
__global__ __launch_bounds__(256,4) void ka_ks(float* out, int d,
                                               unsigned long long sb, unsigned long long db){
  __shared__ __align__(16) float C[2148], Y[2148];
  __shared__ __align__(16) float B1[1152], B2[1152], B3[1152], B4[1152];
  __shared__ float vcz[32], vcm[32];
  int tid=threadIdx.x; int i=blockIdx.x;
  if(i<d){
    const float4* s=(const float4*)(out+sb+(size_t)i*XSLOT);
    float4* dd=(float4*)(out+db+(size_t)i*XSLOT);
    #pragma unroll 3
    for(int q=tid;q<537;q+=256){ float4 v=s[q]; dd[q]=v; if(PUB) ((float4*)C)[q]=v; }
    if(PUB){
      if(i<1023) st_pref(out+O_CROSS, i+1, C, tid);     // pseudo-slot i+1 = exclusive prefix
      if(i==0 && tid==0) out[O_CROSS + 4*1024 + 560 + 288 + 2] = 0.f;  // pseudo-slot 0 flag=0
    }
    return;
  }
  ld_x(C, out, sb, i-d, tid);
  ld_x(Y, out, sb, i,   tid);
  comb_a(C, Y, B1,B2,B3,B4, vcz,vcm, tid);
  st_x(out, db, i, C, tid);
  if(PUB && i<1023) st_pref(out+O_CROSS, i+1, C, tid);
}

// ---------------- A3: propagate + fused apply ----------------
__global__ __launch_bounds__(256,4) void ka_prop(float* wsf, float* out){
  __shared__ __align__(16) float C[2148], Y[2148];
  __shared__ __align__(16) float B1[1152], B2[1152], B3[1152], B4[1152];
  __shared__ float vcz[32], vcm[32], mlv[32], xtv[32], mv[32];
  int tid=threadIdx.x; int i=blockIdx.x;
  ld_pref(C, out + O_CROSS, SAGG0+i, tid);
  if(tid<32){ mlv[tid]=wsf[F_MLAST+tid]; xtv[tid]=wsf[F_XT+tid]; }
  __syncthreads();
  for(int e=0;e<8;++e){
    int j=8*i+e;
    if(j>0){
      int t=NN-j;
      t36_rows(B1, C+BG, tid);
      t36_rows(B4, wsf+F_COVT, tid);
      __syncthreads();
      if(tid<32){
        float am=0.f, az=0.f;
        #pragma unroll
        for(int m=0;m<32;++m){ float g=B1[tid*36+m]; am=fmaf(g,mlv[m],am); az=fmaf(g,xtv[m],az); }
        mv[tid]=am+C[BCM+tid];
        out[O_EX+(size_t)t*32+tid]=mv[tid];
        out[O_Z +(size_t)t*32+tid]=az+C[BCZ+tid];
      }
      #pragma unroll 4
      for(int q=tid;q<1024;q+=256){ int r=q>>5,c=q&31; B2[r*36+c]=dot36(B1,r,B4,c); }
      __syncthreads();
      #pragma unroll 3
      for(int q=tid;q<528;q+=256){
        int r,c; tri_rc(q,r,c);
        float e2 = dot36(B2,r,B1,c) + C[BP+q] + mv[r]*mv[c];
        out[O_EXXT+(size_t)t*1024 + r*32+c]=e2;
        if(r!=c) out[O_EXXT+(size_t)t*1024 + c*32+r]=e2;
      }
    }
    int s=(j<NN)? (NN-j) : 0;
    ld_slot(Y, wsf + F_SCAN + (size_t)s*SSTR, tid);
    comb_a(C, Y, B1,B2,B3,B4, vcz,vcm, tid);
  }
}

// ---------------- Cross_t ----------------
__global__ __launch_bounds__(256,6) void k_cross(float* wsf, float* out){
  __shared__ __align__(16) float PV36[1152], LA36[1152], E136[1152], GF36[1152];
  __shared__ float gv[32], m1[32];
  int tid=threadIdx.x;
  int t = blockIdx.x;
  float* outc = out + O_CROSS + (size_t)t*1024;
  t36_sym (PV36, outc, tid);
  t36_rows(LA36, wsf+F_LAMA, tid);
  t36_rows(E136, out+O_EXXT+(size_t)(t+1)*1024, tid);
  if(tid<32){ gv[tid]=outc[528+tid]; m1[tid]=out[O_EX+(size_t)(t+1)*32+tid]; }
  __syncthreads();
  #pragma unroll 4
  for(int q=tid;q<1024;q+=256){
    int r=q>>5,c=q&31;
    GF36[r*36+c] = dot36(PV36, r, LA36, c);
  }
  __syncthreads();
  #pragma unroll 4
  for(int q=tid;q<1024;q+=256){
    int i2=q>>5, j=q&31;
    float acc = dot36(GF36, j, E136, i2);
    outc[q] = acc + gv[j]*m1[i2];
  }
}

// ---------------- big reduction over t ----------------
__global__ __launch_bounds__(256) void k_terms(const float* rJ, const float* rh,
    const float* plam, float* wsf, double* wsd, float* out){
  __shared__ float slam[1056], slamA[1056], sata[1056];
  __shared__ float slamb[32], satlb[32], cst[16], sw[16];
  __shared__ double sd[256];
  int tid=threadIdx.x; int i8=tid>>3, c4=(tid&7)*4;
  for(int p=0;p<4;p++){int cell=tid+(p<<8);int r=cell>>5,c=cell&31;
    slam[r*33+c]=wsf[F_LAM+cell]; slamA[r*33+c]=wsf[F_LAMA+cell]; sata[r*33+c]=wsf[F_ATLAMA+cell];}
  if(tid<32){slamb[tid]=wsf[F_LAMB+tid]; satlb[tid]=wsf[F_ATLAMB+tid];}
  if(tid<16) cst[tid] = -0.5f*wsf[F_BTLAMBK+tid] + 0.5f*wsf[F_LOGDETK+tid];
  __syncthreads();
  double dr=0.0, dt=0.0, dm=0.0;
  int t0=blockIdx.x*8;
  for(int tt=0;tt<8;++tt){
    int t=t0+tt;
    if(t<NN){ if(tid<16) sw[tid]=out[O_CAT+(size_t)t*16+tid]; }
    __syncthreads();
    size_t cb=(size_t)t*1024+((size_t)i8<<5)+c4;
    float4 exT=*(const float4*)(out+O_EXXT+cb);
    float4 rj =*(const float4*)(rJ+cb);
    dr += -0.5*(double)(rj.x*exT.x+rj.y*exT.y+rj.z*exT.z+rj.w*exT.w);
    if(tid<32) dr += (double)(rh[(size_t)t*32+tid]*out[O_EX+(size_t)t*32+tid]);
    if(t>=1){
      dt += -0.5*(double)(slam[i8*33+c4]*exT.x + slam[i8*33+c4+1]*exT.y
                        + slam[i8*33+c4+2]*exT.z + slam[i8*33+c4+3]*exT.w);
      if(tid<32) dt += (double)(slamb[tid]*out[O_EX+(size_t)t*32+tid]);
    }
    if(t<NN){
      float4 crT =*(const float4*)(out+O_CROSS+cb);
      float4 exT1=*(const float4*)(out+O_EXXT+cb+1024);
      dt += (double)(slamA[i8*33+c4]*crT.x + slamA[i8*33+c4+1]*crT.y
                   + slamA[i8*33+c4+2]*crT.z + slamA[i8*33+c4+3]*crT.w)
          -0.5*(double)(sata[i8*33+c4]*exT.x + sata[i8*33+c4+1]*exT.y
                      + sata[i8*33+c4+2]*exT.z + sata[i8*33+c4+3]*exT.w);
      if(tid<32) dt -= (double)(satlb[tid]*out[O_EX+(size_t)t*32+tid]);
      const float* pe1=(const float*)&exT1; const float* pcr=(const float*)&crT; const float* pe0=(const float*)&exT;
      #pragma unroll
      for(int q=0;q<4;q++){
        int cc=(i8<<5)+c4+q;
        float wl=0.f, wa=0.f, wt2=0.f;
        #pragma unroll
        for(int k2=0;k2<KK;k2++){ float wv=sw[k2];
          wl =fmaf(wv, plam[(size_t)k2*1024+cc], wl);
          wa =fmaf(wv, wsf[F_LAMAK+(size_t)k2*1024+cc], wa);
          wt2=fmaf(wv, wsf[F_ATLAMAK+(size_t)k2*1024+cc], wt2);}
        dm += (double)(-0.5f*wl*pe1[q] + wa*pcr[q] - 0.5f*wt2*pe0[q]);
      }
      if(tid<32){
        float wlb=0.f, wtb=0.f;
        #pragma unroll
        for(int k2=0;k2<KK;k2++){ wlb=fmaf(sw[k2], wsf[F_LAMBK+k2*32+tid], wlb);
                                  wtb=fmaf(sw[k2], wsf[F_ATLAMBK+k2*32+tid], wtb);}
        dm += (double)(wlb*out[O_EX+(size_t)(t+1)*32+tid] - wtb*out[O_EX+(size_t)t*32+tid]);
      }
      if(tid<16) dm += (double)(sw[tid]*cst[tid]);
    }
    __syncthreads();
  }
  double r1=blk_red(dr,sd,tid);
  double r2=blk_red(dt,sd,tid);
  double r3=blk_red(dm,sd,tid);
  if(tid==0){ wsd[WSD_PR+blockIdx.x]=r1; wsd[WSD_PT+blockIdx.x]=r2; wsd[WSD_PM+blockIdx.x]=r3; }
}

__global__ __launch_bounds__(256) void k_final(const float* il, const float* tl,
    const float* ilp, const float* tlp, const float* ptau, float* wsf, double* wsd, float* out){
  __shared__ double sd[256];
  int tid=threadIdx.x;
  double ez=0.0;
  for(int b=0;b<128;++b) ez += (double)wsf[F_EZ + b*256 + tid];
  double v = ez * (double)(tl[tid]-tlp[tid]);
  if(tid<16) v += (double)out[O_CAT+tid] * (double)(il[tid]-ilp[tid]);
  double hmmkl = blk_red(v, sd, tid) - (double)wsf[F_SC+0];
  double a=0,b2=0,c=0;
  for(int q=0;q<4;q++){int b3=tid+q*256; a+=wsd[WSD_PR+b3]; b2+=wsd[WSD_PT+b3]; c+=wsd[WSD_PM+b3];}
  double recog=blk_red(a,sd,tid), trns=blk_red(b2,sd,tid), mixt=blk_red(c,sd,tid);
  double ia=0, ib=0, va=0, vb=0;
  for(int p=0;p<4;p++){int cell=tid+(p<<8);
    float e0=out[O_EXXT+cell];
    ia += (double)(wsf[F_TAU+cell]*e0);
    ib += (double)(ptau[cell]*e0);
  }
  if(tid<32){ float ex0=out[O_EX+tid];
    va=(double)(ex0*wsf[F_TAUMU+tid]); vb=(double)(ex0*wsf[F_TPM+tid]); }
  double s_ia=blk_red(ia,sd,tid), s_ib=blk_red(ib,sd,tid);
  double s_va=blk_red(va,sd,tid), s_vb=blk_red(vb,sd,tid);
  if(tid==0){
    double init_term = -0.5*s_ia + s_va + wsd[WSD_LOGC0];
    double mix_init  = -0.5*s_ib + s_vb + wsd[WSD_MIXC];
    double trans_term = trns + (double)NN*(-0.5*wsd[WSD_BTLAMB] + 0.5*wsd[WSD_LDLAM] - 0.5*Dd*LOG2PI_);
    double mix_trans  = mixt - 0.5*(double)NN*(double)Dd*LOG2PI_;
    double lds_kl = (init_term+trans_term) + recog - wsd[WSD_LOGZQ] - (mix_init+mix_trans);
    out[O_KL] = (float)(lds_kl + hmmkl);
  }
}

// ---------------- launch ----------------
extern "C" void kernel_launch(void* const* d_in, const int* in_sizes, int n_in,
                              void* d_out, int out_size, void* d_ws, size_t ws_size,
                              hipStream_t stream){
  const float* rJ  =(const float*)d_in[0];
  const float* rh  =(const float*)d_in[1];
  const float* loc =(const float*)d_in[2];
  const float* Tp  =(const float*)d_in[3];
  const float* Lp  =(const float*)d_in[4];
  const float* X   =(const float*)d_in[5];
  const float* il  =(const float*)d_in[6];
  const float* tl  =(const float*)d_in[7];
  const float* plam=(const float*)d_in[8];
  const float* pX  =(const float*)d_in[9];
  const float* ptau=(const float*)d_in[10];
  const float* pmu =(const float*)d_in[11];
  const float* ilp =(const float*)d_in[12];
  const float* tlp =(const float*)d_in[13];
  const int*   seed=(const int*)d_in[14];
  float* out=(float*)d_out;
  double* wsd=(double*)d_ws;
  float* wsf=(float*)((char*)d_ws + 32768);

  const unsigned long long XB0 = (unsigned long long)O_EXXT;
  const unsigned long long XB1 = (unsigned long long)O_EXXT + 1024ull*XSLOT;

  k_setup<<<19,256,0,stream>>>(rJ,rh,loc,Tp,Lp,X,plam,pX,ptau,pmu,wsf,wsd);
  k_eps<<<1024,256,0,stream>>>(seed, out + O_Z);
  k_hmmpow<<<1,256,0,stream>>>(tl, wsf);
  k_hmmab<<<32,256,0,stream>>>(il, wsf);
  k_cat<<<128,256,0,stream>>>(tl, wsf, out);
  // filter scan: chunk aggregates -> Kogge-Stone inclusive -> propagate (fused point)
  kf_agg<<<1024,256,0,stream>>>(rJ, rh, wsf, wsd, out, XB0);
  for(int lv=0; lv<10; ++lv){
    unsigned long long sb = (lv&1)? XB1 : XB0;
    unsigned long long db = (lv&1)? XB0 : XB1;
    kf_ks<<<1024,256,0,stream>>>(out, 1<<lv, sb, db);
  }
  kf_prop<<<1024,256,0,stream>>>(rJ, rh, wsf, wsd, out, XB0);
  // affine scan (smoother + sampler): same structure, last KS level publishes prefixes
  ka_agg<<<1024,256,0,stream>>>(wsf, out, XB0);
  for(int lv=0; lv<9; ++lv){
    unsigned long long sb = (lv&1)? XB1 : XB0;
    unsigned long long db = (lv&1)? XB0 : XB1;
    ka_ks<0><<<1024,256,0,stream>>>(out, 1<<lv, sb, db);
  }
  ka_ks<1><<<1024,256,0,stream>>>(out, 512, XB1, XB0);
  ka_prop<<<1024,256,0,stream>>>(wsf, out);
  k_cross<<<NN,256,0,stream>>>(wsf, out);
  k_terms<<<1024,256,0,stream>>>(rJ, rh, plam, wsf, wsd, out);
  k_final<<<1,256,0,stream>>>(il, tl, ilp, tlp, ptau, wsf, wsd, out);
}

// Round 10
// 1697.457 us; speedup vs baseline: 1.7200x; 1.0447x over previous
//
#include <hip/hip_runtime.h>
#include <math.h>
#include <stdint.h>

#define Dd 32
#define TT 8192
#define NN 8191
#define KK 16
#define LOG2PI_ 1.8378770664093453

// ---------------- ws doubles ----------------
#define WSD_LOGC0  0
#define WSD_LOGZQ  1
#define WSD_MIXC   3
#define WSD_LDLAM  4
#define WSD_BTLAMB 5
#define WSD_PR     8
#define WSD_PT     1032
#define WSD_PM     2056
// ---------------- ws floats (base = byte 32768) ----------------
#define F_TAU      0
#define F_TAUMU    1024
#define F_LAM      1056
#define F_A        2080
#define F_B        3104
#define F_ATLAM    3136
#define F_ATLAMA   4160
#define F_LAMA     5184
#define F_LAMB     6208
#define F_ATLAMB   6240
#define F_SC       6272
#define F_LAMAK    6304
#define F_ATLAMAK  22688
#define F_LAMBK    39072
#define F_ATLAMBK  39584
#define F_BTLAMBK  40096
#define F_LOGDETK  40112
#define F_TPM      40128
#define F_J0       40160
#define F_H0       41184
#define F_MLAST    41216
#define F_COVT     41248
#define F_XT       42272
#define F_TPOW     42304
#define F_ALPHA    45632
#define F_BETA     176704
#define F_EZ       307776
#define F_SCAN     340544

// scan slot layout (stride 2148 floats)
#define SSTR   2148
#define POFF   0
#define QOFF   528
#define ROFF   1056
#define PPOFF  2080
#define QQOFF  2112
#define GAMOFF 2144
#define FLGOFF 2146
// affine leaf/composite layout
#define BG     0
#define BCZ    1024
#define BCM    1056
#define BP     1088

// out offsets (floats)
#define O_Z     ((size_t)0)
#define O_EX    ((size_t)262144)
#define O_EXXT  ((size_t)524288)
#define O_CROSS ((size_t)8912896)
#define O_CAT   ((size_t)17300480)
#define O_KL    ((size_t)17431536)

// KS scratch in dead EXXT zone (plain stride-2176 slots)
#define XSLOT  2176
#define SAGG0  0

// ---------------- threefry ----------------
__device__ __forceinline__ uint32_t rotl32(uint32_t v, int d){ return (v<<d)|(v>>(32-d)); }
__device__ __forceinline__ void threefry2x32(uint32_t k0, uint32_t k1, uint32_t x0, uint32_t x1,
                                             uint32_t& o0, uint32_t& o1){
  uint32_t ks2 = k0 ^ k1 ^ 0x1BD11BDAu;
  x0 += k0; x1 += k1;
  x0+=x1; x1=rotl32(x1,13); x1^=x0;  x0+=x1; x1=rotl32(x1,15); x1^=x0;
  x0+=x1; x1=rotl32(x1,26); x1^=x0;  x0+=x1; x1=rotl32(x1, 6); x1^=x0;
  x0+=k1; x1+=ks2+1u;
  x0+=x1; x1=rotl32(x1,17); x1^=x0;  x0+=x1; x1=rotl32(x1,29); x1^=x0;
  x0+=x1; x1=rotl32(x1,16); x1^=x0;  x0+=x1; x1=rotl32(x1,24); x1^=x0;
  x0+=ks2; x1+=k0+2u;
  x0+=x1; x1=rotl32(x1,13); x1^=x0;  x0+=x1; x1=rotl32(x1,15); x1^=x0;
  x0+=x1; x1=rotl32(x1,26); x1^=x0;  x0+=x1; x1=rotl32(x1, 6); x1^=x0;
  x0+=k0; x1+=k1+3u;
  x0+=x1; x1=rotl32(x1,17); x1^=x0;  x0+=x1; x1=rotl32(x1,29); x1^=x0;
  x0+=x1; x1=rotl32(x1,16); x1^=x0;  x0+=x1; x1=rotl32(x1,24); x1^=x0;
  x0+=k1; x1+=ks2+4u;
  x0+=x1; x1=rotl32(x1,13); x1^=x0;  x0+=x1; x1=rotl32(x1,15); x1^=x0;
  x0+=x1; x1=rotl32(x1,26); x1^=x0;  x0+=x1; x1=rotl32(x1, 6); x1^=x0;
  x0+=ks2; x1+=k0+5u;
  o0=x0; o1=x1;
}
__device__ __forceinline__ float tf_normal(uint32_t bits){
  float fl = __uint_as_float((bits>>9) | 0x3F800000u) - 1.0f;
  const float lo = -0.99999994f;
  float u = fmaxf(lo, fl*2.0f + lo);
  float w = -log1pf(-u*u);
  float p;
  if (w < 5.0f){
    w -= 2.5f;
    p = 2.81022636e-08f;
    p = fmaf(p,w,3.43273939e-07f); p = fmaf(p,w,-3.5233877e-06f);
    p = fmaf(p,w,-4.39150654e-06f); p = fmaf(p,w,0.00021858087f);
    p = fmaf(p,w,-0.00125372503f); p = fmaf(p,w,-0.00417768164f);
    p = fmaf(p,w,0.246640727f); p = fmaf(p,w,1.50140941f);
  } else {
    w = sqrtf(w) - 3.0f;
    p = -0.000200214257f;
    p = fmaf(p,w,0.000100950558f); p = fmaf(p,w,0.00134934322f);
    p = fmaf(p,w,-0.00367342844f); p = fmaf(p,w,0.00573950773f);
    p = fmaf(p,w,-0.0076224613f); p = fmaf(p,w,0.00943887047f);
    p = fmaf(p,w,1.00167406f); p = fmaf(p,w,2.83297682f);
  }
  return 1.4142135381698608f * (p*u);
}

// ---------------- helpers ----------------
__device__ __forceinline__ void tri_rc(int i, int& r, int& c){
  int rr = (int)((sqrtf(8.f*(float)i+1.f)-1.f)*0.5f);
  while((rr+1)*(rr+2)/2 <= i) ++rr;
  while(rr*(rr+1)/2 > i) --rr;
  r = rr; c = i - rr*(rr+1)/2;
}

__device__ __forceinline__ float dot36(const float* A, int r, const float* B, int c){
  const float4* a4 = (const float4*)(A + r*36);
  const float4* b4 = (const float4*)(B + c*36);
  float sx=0.f, sy=0.f, sz=0.f, sw=0.f;
  #pragma unroll
  for(int m=0;m<8;++m){
    float4 a=a4[m], b=b4[m];
    sx=fmaf(a.x,b.x,sx); sy=fmaf(a.y,b.y,sy);
    sz=fmaf(a.z,b.z,sz); sw=fmaf(a.w,b.w,sw);
  }
  return (sx+sy)+(sz+sw);
}
// 4 dots sharing a fixed B-row (hoisted to registers): rows rbase+8k of A
__device__ __forceinline__ void dot36_x4(const float* A, int rbase, const float* B, int bfix, float* res){
  const float4* b4 = (const float4*)(B + bfix*36);
  float4 bb[8];
  #pragma unroll
  for(int m=0;m<8;++m) bb[m]=b4[m];
  #pragma unroll
  for(int k=0;k<4;++k){
    const float4* a4 = (const float4*)(A + (rbase+8*k)*36);
    float sx=0.f, sy=0.f, sz=0.f, sw=0.f;
    #pragma unroll
    for(int m=0;m<8;++m){
      float4 a=a4[m], b=bb[m];
      sx=fmaf(a.x,b.x,sx); sy=fmaf(a.y,b.y,sy);
      sz=fmaf(a.z,b.z,sz); sw=fmaf(a.w,b.w,sw);
    }
    res[k]=(sx+sy)+(sz+sw);
  }
}
__device__ __forceinline__ void t36_rows(float* dst, const float* src, int tid){
  int r=tid>>3, c0=(tid&7)<<2;
  *(float4*)(dst + r*36 + c0) = *(const float4*)(src + r*32 + c0);
}
__device__ __forceinline__ void t36_tr(float* dst, const float* src, int tid){
  int m=tid>>3, j0=(tid&7)<<2;
  float4 v = *(const float4*)(src + m*32 + j0);
  dst[(j0+0)*36+m]=v.x; dst[(j0+1)*36+m]=v.y;
  dst[(j0+2)*36+m]=v.z; dst[(j0+3)*36+m]=v.w;
}
__device__ __forceinline__ void t36_tr36(float* dst, const float* src, int tid){
  int m=tid>>3, j0=(tid&7)<<2;
  float4 v = *(const float4*)(src + m*36 + j0);
  dst[(j0+0)*36+m]=v.x; dst[(j0+1)*36+m]=v.y;
  dst[(j0+2)*36+m]=v.z; dst[(j0+3)*36+m]=v.w;
}
__device__ __forceinline__ void t36_sym(float* dst, const float* packed, int tid){
  for(int q=tid;q<528;q+=256){
    int r,c; tri_rc(q,r,c);
    float v=packed[q];
    dst[r*36+c]=v; dst[c*36+r]=v;
  }
}

// slot IO: full 2148-float slots (wsf scan slots)
__device__ __forceinline__ void ld_slot(float* dst, const float* src, int tid){
  #pragma unroll 3
  for(int q=tid;q<537;q+=256) ((float4*)dst)[q] = ((const float4*)src)[q];
}
// scratch pseudo-slot p stored in tails (floats 560..1023) of O_CROSS slots 5p..5p+4
__device__ __forceinline__ void st_pref(float* cb, int p, const float* C, int tid){
  #pragma unroll 3
  for(int q=tid;q<537;q+=256){
    int w=q/116, o=(q-116*w)<<2;
    *(float4*)(cb + (((size_t)(5*p+w))<<10) + 560 + o) = ((const float4*)C)[q];
  }
}
__device__ __forceinline__ void ld_pref(float* C, const float* cb, int p, int tid){
  #pragma unroll 3
  for(int q=tid;q<537;q+=256){
    int w=q/116, o=(q-116*w)<<2;
    ((float4*)C)[q] = *(const float4*)(cb + (((size_t)(5*p+w))<<10) + 560 + o);
  }
}
// KS scratch IO: plain stride-XSLOT slots at absolute float base
__device__ __forceinline__ void ld_x(float* C, const float* out, unsigned long long base, int i, int tid){
  const float4* src = (const float4*)(out + base + (size_t)i*XSLOT);
  #pragma unroll 3
  for(int q=tid;q<537;q+=256) ((float4*)C)[q] = src[q];
}
__device__ __forceinline__ void st_x(float* out, unsigned long long base, int i, const float* C, int tid){
  float4* dst = (float4*)(out + base + (size_t)i*XSLOT);
  #pragma unroll 3
  for(int q=tid;q<537;q+=256) dst[q] = ((const float4*)C)[q];
}

// Fused cholesky + L^-1, quad-vectorized, stride 36.
__device__ double chol_linv36(float* W, float* Li, float* rdg, int tid){
  int r = tid>>3, c0 = (tid&7)<<2;
  {
    float4 z = make_float4(0.f,0.f,0.f,0.f);
    if(r>=c0 && r<c0+4) ((float*)&z)[r-c0]=1.f;
    *(float4*)(Li + r*36 + c0) = z;
  }
  double slog=0.0;
  for(int j=0;j<33;++j){
    if(j<32){
      float dd = W[j*36+j];
      float rd = 1.0f/sqrtf(dd);
      float invd = rd*rd;
      if(tid==0){ rdg[j]=rd; slog += (double)(0.5f*__logf(dd)); }
      if(r>j && c0+3>=j){
        float t0 = W[j*36+r]*invd;
        float4 wj  = *(const float4*)(W+j*36+c0);
        float4 cur = *(float4*)(W+r*36+c0);
        float rdl = rd;
        int c;
        c=c0;   cur.x = (c>j)? fmaf(-t0, wj.x, cur.x) : ((c==j)? cur.x*rdl : cur.x);
        c=c0+1; cur.y = (c>j)? fmaf(-t0, wj.y, cur.y) : ((c==j)? cur.y*rdl : cur.y);
        c=c0+2; cur.z = (c>j)? fmaf(-t0, wj.z, cur.z) : ((c==j)? cur.z*rdl : cur.z);
        c=c0+3; cur.w = (c>j)? fmaf(-t0, wj.w, cur.w) : ((c==j)? cur.w*rdl : cur.w);
        *(float4*)(W+r*36+c0) = cur;
      }
    }
    if(j>0){
      int ii=j-1;
      if(r>ii && c0<=ii){
        float wri = W[r*36+ii]*rdg[ii];
        float4 lrow = *(const float4*)(Li+ii*36+c0);
        float4 cur  = *(float4*)(Li+r*36+c0);
        if(c0+0<=ii) cur.x = fmaf(-wri, lrow.x, cur.x);
        if(c0+1<=ii) cur.y = fmaf(-wri, lrow.y, cur.y);
        if(c0+2<=ii) cur.z = fmaf(-wri, lrow.z, cur.z);
        if(c0+3<=ii) cur.w = fmaf(-wri, lrow.w, cur.w);
        *(float4*)(Li+r*36+c0) = cur;
      }
    }
    __syncthreads();
  }
  {
    float rr = rdg[r];
    float4 cur = *(float4*)(Li+r*36+c0);
    cur.x*=rr; cur.y*=rr; cur.z*=rr; cur.w*=rr;
    *(float4*)(Li+r*36+c0) = cur;
  }
  __syncthreads();
  return slog;
}

__device__ __forceinline__ double blk_red(double v, double* sd, int tid){
  sd[tid]=v; __syncthreads();
  for(int s=128;s>0;s>>=1){ if(tid<s) sd[tid]+=sd[tid+s]; __syncthreads(); }
  double r=sd[0]; __syncthreads(); return r;
}
__device__ double blk_logdet(float* Ms, int tid){
  double sl = 0.0;
  for (int j=0;j<Dd;++j){
    float dd = Ms[j*33+j];
    sl += log((double)dd);
    float invd = 1.0f/dd;
    #pragma unroll
    for(int p=0;p<4;p++){
      int cell = tid + (p<<8); int r=cell>>5, c=cell&31;
      if(r>j && c>j && c<=r) Ms[r*33+c] -= Ms[r*33+j]*(Ms[c*33+j]*invd);
    }
    __syncthreads();
  }
  return sl;
}

// ---------- filter-scan device pieces ----------
__device__ void unary_f(float* C, const float* wsf, const double* wsd, int tid){
  __syncthreads();
  #pragma unroll 3
  for(int q=tid;q<528;q+=256){
    int r,c; tri_rc(q,r,c);
    C[POFF+q]=0.f;
    C[QOFF+q]=wsf[F_J0 + r*32+c];
  }
  #pragma unroll 4
  for(int q=tid;q<1024;q+=256) C[ROFF+q]=0.f;
  if(tid<32){ C[PPOFF+tid]=0.f; C[QQOFF+tid]=wsf[F_H0+tid]; }
  if(tid==0){ *(double*)(C+GAMOFF)=wsd[WSD_LOGC0]; C[FLGOFF]=1.f; }
}
__device__ void leaf_f(float* C, int t, const float* rJ, const float* rh,
                       const float* wsf, const double* wsd, int tid){
  __syncthreads();
  #pragma unroll 3
  for(int q=tid;q<528;q+=256){
    int r,c; tri_rc(q,r,c);
    C[POFF+q] = wsf[F_ATLAMA + r*32+c] + ((r==c)?1e-6f:0.f);
    C[QOFF+q] = wsf[F_LAM + r*32+c] + rJ[(size_t)t*1024 + r*32+c];
  }
  #pragma unroll 4
  for(int q=tid;q<1024;q+=256) C[ROFF+q] = -wsf[F_ATLAM+q];
  if(tid<32){
    C[PPOFF+tid] = -wsf[F_ATLAMB+tid];
    C[QQOFF+tid] = wsf[F_LAMB+tid] + rh[(size_t)t*32+tid];
  }
  if(tid==0){
    *(double*)(C+GAMOFF) = -0.5*wsd[WSD_BTLAMB] + 0.5*wsd[WSD_LDLAM];
    C[FLGOFF]=1.f;
  }
}

// general filter combine, in-place on C (LDS); Y in LDS. C earlier, Y later.
__device__ void comb_f(float* C, const float* Y, float* W, float* Li, float* BA, float* BB,
                       float* rdg, float* Ls, int tid){
  __syncthreads();
  int fc=(C[FLGOFF]!=0.f), fy=(Y[FLGOFF]!=0.f);
  if(fy && !fc){
    #pragma unroll 3
    for(int q=tid;q<537;q+=256) ((float4*)C)[q]=((const float4*)Y)[q];
  } else if(fy){
    #pragma unroll 3
    for(int q=tid;q<528;q+=256){
      int r,c; tri_rc(q,r,c);
      float w = C[QOFF+q] + Y[POFF+q];
      W[r*36+c]=w; W[c*36+r]=w;
    }
    t36_rows(BA, C+ROFF, tid);
    t36_tr  (BB, Y+ROFF, tid);
    __syncthreads();
    double slog = chol_linv36(W, Li, rdg, tid);
    if(tid<32){
      float acc=0.f;
      for(int m=0;m<=tid;++m) acc=fmaf(Li[tid*36+m], C[QQOFF+m]+Y[PPOFF+m], acc);
      Ls[tid]=acc;
    }
    {   // T1t: W[j][i2] = dot(Li[i2], BA[j]), j=tid&31, i2=rb+8k
      int j=tid&31, rb=tid>>5; float res[4];
      dot36_x4(Li, rb, BA, j, res);
      #pragma unroll
      for(int k=0;k<4;++k) W[j*36+rb+8*k]=res[k];
    }
    __syncthreads();
    {   // T2t: BA[j][i2] = dot(Li[i2], BB[j])
      int j=tid&31, rb=tid>>5; float res[4];
      dot36_x4(Li, rb, BB, j, res);
      __syncthreads();            // all reads of BA (T1t src) done? (T1t read BA before barrier; safe)
      #pragma unroll
      for(int k=0;k<4;++k) BA[j*36+rb+8*k]=res[k];
    }
    __syncthreads();
    #pragma unroll 3
    for(int q=tid;q<528;q+=256){
      int r,c; tri_rc(q,r,c);
      C[POFF+q] = C[POFF+q] - dot36(W,r,W,c);
      C[QOFF+q] = Y[QOFF+q] - dot36(BA,r,BA,c);
    }
    {   // R: C[R + r*32+c] = -dot(W[r], BA[c]), c=tid&31, r=rb+8k
      int c=tid&31, rb=tid>>5; float res[4];
      dot36_x4(W, rb, BA, c, res);
      #pragma unroll
      for(int k=0;k<4;++k) C[ROFF+(rb+8*k)*32+c] = -res[k];
    }
    if(tid<32){
      float ap=0.f,aq=0.f;
      #pragma unroll
      for(int m=0;m<32;++m){ ap=fmaf(W[tid*36+m],Ls[m],ap); aq=fmaf(BA[tid*36+m],Ls[m],aq); }
      C[PPOFF+tid] -= ap;
      C[QQOFF+tid] = Y[QQOFF+tid] - aq;
    }
    if(tid==0){
      double g = *(double*)(C+GAMOFF) + *(const double*)(Y+GAMOFF);
      double dot=0.0;
      for(int m=0;m<32;++m) dot += (double)Ls[m]*(double)Ls[m];
      *(double*)(C+GAMOFF) = g + 0.5*dot - slog;
    }
  }
  __syncthreads();
}

// specialized advance with leaf t (shares chol with optional point output for t-1)
template<int POINT>
__device__ void adv_leaf_f(float* C, int t, const float* rJ, const float* rh,
                           const float* wsf, const double* wsd,
                           const float* CLAMA, const float* CATA, const float* catb,
                           float* W, float* Li, float* BA, float* BB,
                           float* rdg, float* Lu, float* uv, float* ev,
                           float* pe, float* outc, const float* outz, int tid){
  __syncthreads();
  #pragma unroll 3
  for(int q=tid;q<528;q+=256){
    int r,c; tri_rc(q,r,c);
    float w = C[QOFF+q] + CATA[r*36+c];
    W[r*36+c]=w; W[c*36+r]=w;
  }
  t36_rows(BB, C+ROFF, tid);
  if(tid<32){
    uv[tid] = C[QQOFF+tid] - catb[tid];
    if(POINT) ev[tid] = outz[(size_t)(t-1)*32+tid];
  }
  __syncthreads();
  double slog = chol_linv36(W, Li, rdg, tid);
  if(tid<32){
    float acc=0.f;
    for(int m=0;m<=tid;++m) acc=fmaf(Li[tid*36+m], uv[m], acc);
    Lu[tid]=acc;
  }
  {   // T1t: W[j][i2] = dot(Li[i2], BB[j])
    int j=tid&31, rb=tid>>5; float res[4];
    dot36_x4(Li, rb, BB, j, res);
    #pragma unroll
    for(int k=0;k<4;++k) W[j*36+rb+8*k]=res[k];
  }
  __syncthreads();
  {   // TA: BA[j][i2] = dot(Li[i2], CLAMA[j])
    int j=tid&31, rb=tid>>5; float res[4];
    dot36_x4(Li, rb, CLAMA, j, res);
    #pragma unroll
    for(int k=0;k<4;++k) BA[j*36+rb+8*k]=res[k];
  }
  __syncthreads();
  if(POINT){
    t36_tr36(BB, Li, tid);    // BB = LiT rows
    __syncthreads();
    {   // G: pe[BG + r*32+c] = dot(BB[r], BA[c])
      int c=tid&31, rb=tid>>5; float res[4];
      dot36_x4(BB, rb, BA, c, res);
      #pragma unroll
      for(int k=0;k<4;++k) pe[BG+(rb+8*k)*32+c]=res[k];
    }
    #pragma unroll 3
    for(int q=tid;q<528;q+=256){ int r,c; tri_rc(q,r,c); float a=dot36(BB,r,BB,c); pe[BP+q]=a; outc[q]=a; }
    if(tid<32){
      float ag=0.f, ay=0.f;
      for(int m2=tid;m2<32;++m2){ float lv=Li[m2*36+tid]; ag=fmaf(lv,Lu[m2],ag); ay=fmaf(lv,ev[m2],ay); }
      pe[BCM+tid]=ag; pe[BCZ+tid]=ag+ay; outc[528+tid]=ag;
    }
    if(tid==0) pe[FLGOFF]=1.f;
  }
  // advance writes (in-place on C)
  #pragma unroll 3
  for(int q=tid;q<528;q+=256){
    int r,c; tri_rc(q,r,c);
    C[POFF+q] = C[POFF+q] - dot36(W,r,W,c);
    C[QOFF+q] = (wsf[F_LAM + r*32+c] + rJ[(size_t)t*1024 + r*32+c]) - dot36(BA,r,BA,c);
  }
  {   // R: C[R + r*32+c] = dot(W[r], BA[c])
    int c=tid&31, rb=tid>>5; float res[4];
    dot36_x4(W, rb, BA, c, res);
    #pragma unroll
    for(int k=0;k<4;++k) C[ROFF+(rb+8*k)*32+c]=res[k];
  }
  if(tid<32){
    float ap=0.f,aq=0.f;
    #pragma unroll
    for(int m=0;m<32;++m){ ap=fmaf(W[tid*36+m],Lu[m],ap); aq=fmaf(BA[tid*36+m],Lu[m],aq); }
    C[PPOFF+tid] -= ap;
    C[QQOFF+tid] = (wsf[F_LAMB+tid] + rh[(size_t)t*32+tid]) + aq;
  }
  if(tid==0){
    double dot=0.0;
    for(int m=0;m<32;++m) dot += (double)Lu[m]*(double)Lu[m];
    *(double*)(C+GAMOFF) += (-0.5*wsd[WSD_BTLAMB] + 0.5*wsd[WSD_LDLAM]) + 0.5*dot - slog;
  }
}

// final-state from total C (block 1023 of kf_prop)
__device__ void final_f(float* C, float* W, float* Li, float* BB,
                        float* rdg, float* Lu, float* uv, float* ev, float* gv,
                        float* wsf, double* wsd, float* out, int tid){
  __syncthreads();
  #pragma unroll 3
  for(int q=tid;q<528;q+=256){
    int r,c; tri_rc(q,r,c);
    float w = C[QOFF+q] + ((r==c)?1e-6f:0.f);
    W[r*36+c]=w; W[c*36+r]=w;
  }
  if(tid<32){ uv[tid]=C[QQOFF+tid]; ev[tid]=out[O_Z+(size_t)NN*32+tid]; }
  __syncthreads();
  double slog2 = chol_linv36(W, Li, rdg, tid);
  if(tid<32){
    float acc=0.f;
    for(int m=0;m<=tid;++m) acc=fmaf(Li[tid*36+m], uv[m], acc);
    Lu[tid]=acc;
  }
  t36_tr36(BB, Li, tid);
  __syncthreads();
  if(tid<32){
    float am=0.f, ay=0.f;
    for(int m2=tid;m2<32;++m2){ float lv=Li[m2*36+tid]; am=fmaf(lv,Lu[m2],am); ay=fmaf(lv,ev[m2],ay); }
    gv[tid]=am;
    wsf[F_MLAST+tid]=am; out[O_EX+(size_t)NN*32+tid]=am;
    float xt=am+ay;
    wsf[F_XT+tid]=xt; out[O_Z+(size_t)NN*32+tid]=xt;
  }
  __syncthreads();
  {
    int c=tid&31, rb=tid>>5; float res[4];
    dot36_x4(BB, rb, BB, c, res);
    #pragma unroll
    for(int k=0;k<4;++k){
      int q=(rb+8*k)*32+c;
      wsf[F_COVT+q]=res[k];
      out[O_EXXT+(size_t)NN*1024+q]=res[k]+gv[rb+8*k]*gv[c];
    }
  }
  if(tid==0){
    double gam=*(double*)(C+GAMOFF);
    double hm=0.0;
    for(int m=0;m<32;++m) hm += (double)uv[m]*(double)gv[m];
    wsd[WSD_LOGZQ] = gam + 0.5*hm + 0.5*Dd*LOG2PI_ - slog2;
  }
}

// ---------- affine-scan device pieces ----------
// general affine combine, in-place on C; result = Y∘X (C earlier, Y later)
__device__ void comb_a(float* C, const float* Y, float* B1, float* B2, float* B3, float* B4,
                       float* vcz, float* vcm, int tid){
  __syncthreads();
  int fc=(C[FLGOFF]!=0.f), fy=(Y[FLGOFF]!=0.f);
  if(fy && !fc){
    #pragma unroll 3
    for(int q=tid;q<537;q+=256) ((float4*)C)[q]=((const float4*)Y)[q];
  } else if(fy){
    t36_rows(B1, Y+BG, tid);
    t36_tr  (B3, C+BG, tid);
    t36_sym (B4, C+BP, tid);
    if(tid<32){ vcz[tid]=C[BCZ+tid]; vcm[tid]=C[BCM+tid]; }
    __syncthreads();
    {   // G: C[BG + r*32+c] = dot(B1[r], B3[c])
      int c=tid&31, rb=tid>>5; float res[4];
      dot36_x4(B1, rb, B3, c, res);
      #pragma unroll
      for(int k=0;k<4;++k) C[BG+(rb+8*k)*32+c]=res[k];
    }
    {   // S: B2[r][c] = dot(B1[r], B4[c])
      int c=tid&31, rb=tid>>5; float res[4];
      dot36_x4(B1, rb, B4, c, res);
      #pragma unroll
      for(int k=0;k<4;++k) B2[(rb+8*k)*36+c]=res[k];
    }
    __syncthreads();
    #pragma unroll 3
    for(int q=tid;q<528;q+=256){ int r,c; tri_rc(q,r,c); C[BP+q]=dot36(B2,r,B1,c)+Y[BP+q]; }
    if(tid<32){
      float az=0.f,am=0.f;
      #pragma unroll
      for(int m=0;m<32;++m){ float g=B1[tid*36+m]; az=fmaf(g,vcz[m],az); am=fmaf(g,vcm[m],am); }
      C[BCZ+tid]=az+Y[BCZ+tid];
      C[BCM+tid]=am+Y[BCM+tid];
    }
  }
  __syncthreads();
}

// ---------------- setup: 19 independent blocks ----------------
__global__ __launch_bounds__(256) void k_setup(const float* rJ, const float* rh, const float* loc,
    const float* Tp, const float* Lp, const float* X, const float* plam, const float* pX,
    const float* ptau, const float* pmu, float* wsf, double* wsd){
  __shared__ float s1[1056], s2[1056], s3[1056];
  __shared__ float sv[32], sv2[32];
  int tid=threadIdx.x; int b=blockIdx.x;
  if(b==0){
    for(int p=0;p<4;p++){int cell=tid+(p<<8);int r=cell>>5,c=cell&31; s1[r*33+c]=Tp[cell];}
    if(tid<32) sv[tid]=loc[tid];
    __syncthreads();
    for(int p=0;p<4;p++){int cell=tid+(p<<8);int r=cell>>5,c=cell&31;
      float a=0.f;
      #pragma unroll
      for(int m=0;m<Dd;++m) a=fmaf(s1[r*33+m], s1[c*33+m], a);
      if(r==c) a+=1e-8f;
      s2[r*33+c]=a; wsf[F_TAU+cell]=a; wsf[F_J0+cell]=a+rJ[cell];
    }
    __syncthreads();
    if(tid<32){ float tm=0.f;
      #pragma unroll
      for(int m=0;m<Dd;++m) tm=fmaf(s2[tid*33+m], sv[m], tm);
      sv2[tid]=tm; wsf[F_TAUMU+tid]=tm; wsf[F_H0+tid]=tm+rh[tid];
    }
    __syncthreads();
    double ldt = blk_logdet(s2, tid);
    if(tid==0){ double dd=0; for(int m=0;m<Dd;++m) dd += (double)sv[m]*(double)sv2[m];
      wsd[WSD_LOGC0] = -0.5*dd + 0.5*ldt - 0.5*Dd*LOG2PI_; }
  } else if(b==1){
    for(int p=0;p<4;p++){int cell=tid+(p<<8);int r=cell>>5,c=cell&31; s1[r*33+c]=Lp[cell];}
    __syncthreads();
    for(int p=0;p<4;p++){int cell=tid+(p<<8);int r=cell>>5,c=cell&31;
      float a=0.f;
      #pragma unroll
      for(int m=0;m<Dd;++m) a=fmaf(s1[r*33+m], s1[c*33+m], a);
      if(r==c) a+=1e-8f;
      s2[r*33+c]=a; wsf[F_LAM+cell]=a;
    }
    __syncthreads();
    for(int p=0;p<4;p++){int cell=tid+(p<<8);int r=cell>>5,c=cell&31;
      float a=X[r*33+c]; s3[r*33+c]=a; wsf[F_A+cell]=a; }
    if(tid<32){ sv[tid]=X[tid*33+32]; wsf[F_B+tid]=sv[tid]; }
    __syncthreads();
    for(int p=0;p<4;p++){int cell=tid+(p<<8);int r=cell>>5,c=cell&31;
      float a=0.f,b2=0.f;
      #pragma unroll
      for(int m=0;m<Dd;++m){ a=fmaf(s2[r*33+m], s3[m*33+c], a); b2=fmaf(s3[m*33+r], s2[m*33+c], b2); }
      s1[r*33+c]=a; wsf[F_LAMA+cell]=a; wsf[F_ATLAM+cell]=b2;
    }
    if(tid<32){ float lb=0.f;
      #pragma unroll
      for(int m=0;m<Dd;++m) lb=fmaf(s2[tid*33+m], sv[m], lb);
      sv2[tid]=lb; wsf[F_LAMB+tid]=lb;
    }
    __syncthreads();
    for(int p=0;p<4;p++){int cell=tid+(p<<8);int r=cell>>5,c=cell&31;
      float a=0.f;
      #pragma unroll
      for(int m=0;m<Dd;++m) a=fmaf(s3[m*33+r], s1[m*33+c], a);
      wsf[F_ATLAMA+cell]=a;
    }
    if(tid<32){ float ab=0.f;
      #pragma unroll
      for(int m=0;m<Dd;++m) ab=fmaf(s3[m*33+tid], sv2[m], ab);
      wsf[F_ATLAMB+tid]=ab;
    }
    if(tid==0){ double bb=0; for(int m=0;m<Dd;++m) bb += (double)sv[m]*(double)sv2[m];
      wsd[WSD_BTLAMB]=bb; }
    __syncthreads();
    double ldl = blk_logdet(s2, tid);
    if(tid==0) wsd[WSD_LDLAM]=ldl;
  } else if(b==2){
    for(int p=0;p<4;p++){int cell=tid+(p<<8);int r=cell>>5,c=cell&31; s1[r*33+c]=ptau[cell];}
    if(tid<32) sv[tid]=pmu[tid];
    __syncthreads();
    if(tid<32){ float tm=0.f;
      #pragma unroll
      for(int m=0;m<Dd;++m) tm=fmaf(s1[tid*33+m], sv[m], tm);
      sv2[tid]=tm; wsf[F_TPM+tid]=tm;
    }
    __syncthreads();
    double ldp = blk_logdet(s1, tid);
    if(tid==0){ double dd=0; for(int m=0;m<Dd;++m) dd += (double)sv[m]*(double)sv2[m];
      wsd[WSD_MIXC] = -0.5*dd + 0.5*ldp - 0.5*Dd*LOG2PI_; }
  } else {
    int k2 = b-3;
    for(int p=0;p<4;p++){int cell=tid+(p<<8);int r=cell>>5,c=cell&31;
      s2[r*33+c]=plam[k2*1024+cell]; s3[r*33+c]=pX[k2*1056 + r*33 + c];}
    if(tid<32) sv[tid]=pX[k2*1056 + tid*33 + 32];
    __syncthreads();
    for(int p=0;p<4;p++){int cell=tid+(p<<8);int r=cell>>5,c=cell&31;
      float a=0.f;
      #pragma unroll
      for(int m=0;m<Dd;++m) a=fmaf(s2[r*33+m], s3[m*33+c], a);
      s1[r*33+c]=a; wsf[F_LAMAK + (size_t)k2*1024 + cell]=a;
    }
    if(tid<32){ float lb=0.f;
      #pragma unroll
      for(int m=0;m<Dd;++m) lb=fmaf(s2[tid*33+m], sv[m], lb);
      sv2[tid]=lb; wsf[F_LAMBK + k2*32 + tid]=lb;
    }
    __syncthreads();
    for(int p=0;p<4;p++){int cell=tid+(p<<8);int r=cell>>5,c=cell&31;
      float a=0.f;
      #pragma unroll
      for(int m=0;m<Dd;++m) a=fmaf(s3[m*33+r], s1[m*33+c], a);
      wsf[F_ATLAMAK + (size_t)k2*1024 + cell]=a;
    }
    if(tid<32){ float ab=0.f;
      #pragma unroll
      for(int m=0;m<Dd;++m) ab=fmaf(s3[m*33+tid], sv2[m], ab);
      wsf[F_ATLAMBK + k2*32 + tid]=ab;
    }
    if(tid==0){ float bb=0.f; for(int m=0;m<Dd;++m) bb=fmaf(sv[m],sv2[m],bb);
      wsf[F_BTLAMBK + k2]=bb; }
    __syncthreads();
    double dk = blk_logdet(s2, tid);
    if(tid==0) wsf[F_LOGDETK + k2]=(float)dk;
  }
}

// ---------------- eps ----------------
__global__ __launch_bounds__(256) void k_eps(const int* seedp, float* outz){
  uint32_t seed = (uint32_t)seedp[0];
  uint32_t K0,K1;
  threefry2x32(0u, seed, 0u, 1u, K0, K1);
  uint32_t i = blockIdx.x*256u + threadIdx.x;
  uint32_t o0,o1;
  threefry2x32(K0, K1, 0u, i, o0, o1);
  outz[i] = tf_normal(o0 ^ o1);
}

// ---------------- HMM ----------------
__global__ __launch_bounds__(256) void k_hmmpow(const float* tl, float* wsf){
  __shared__ float A0[256], A1[256];
  int tid=threadIdx.x;
  A0[tid]=tl[tid];
  wsf[F_TPOW+tid]=A0[tid];
  __syncthreads();
  float* cur=A0; float* nxt=A1;
  for(int k=1;k<13;++k){
    int i=tid>>4, j=tid&15;
    float mx=-3.0e38f;
    #pragma unroll
    for(int m=0;m<16;++m) mx=fmaxf(mx, cur[i*16+m]+cur[m*16+j]);
    float s=0.f;
    #pragma unroll
    for(int m=0;m<16;++m) s+=__expf(cur[i*16+m]+cur[m*16+j]-mx);
    float v=mx+__logf(s);
    nxt[tid]=v; wsf[F_TPOW+k*256+tid]=v;
    __syncthreads();
    float* t2=cur; cur=nxt; nxt=t2;
  }
}

__global__ __launch_bounds__(256) void k_hmmab(const float* il, float* wsf){
  __shared__ float S[3328];
  int tid=threadIdx.x;
  for(int p=0;p<13;++p) S[p*256+tid]=wsf[F_TPOW+p*256+tid];
  __syncthreads();
  int n = blockIdx.x*256 + tid;
  if(n>NN-1) return;
  float v[16], w[16];
  #pragma unroll
  for(int j=0;j<16;++j) v[j]=il[j];
  for(int k=0;k<13;++k){
    if((n>>k)&1){
      #pragma unroll
      for(int j=0;j<16;++j){
        float mx=-3.0e38f;
        #pragma unroll
        for(int i2=0;i2<16;++i2) mx=fmaxf(mx, v[i2]+S[k*256+i2*16+j]);
        float s=0.f;
        #pragma unroll
        for(int i2=0;i2<16;++i2) s+=__expf(v[i2]+S[k*256+i2*16+j]-mx);
        w[j]=mx+__logf(s);
      }
      #pragma unroll
      for(int j=0;j<16;++j) v[j]=w[j];
    }
  }
  #pragma unroll
  for(int j=0;j<16;++j) wsf[F_ALPHA+(size_t)n*16+j]=v[j];
  if(n==NN-1){
    float mx=-3.0e38f;
    #pragma unroll
    for(int j=0;j<16;++j) mx=fmaxf(mx,v[j]);
    float s=0.f;
    #pragma unroll
    for(int j=0;j<16;++j) s+=__expf(v[j]-mx);
    wsf[F_SC+0]=mx+__logf(s);
  }
  int m = NN-1-n;
  float b[16];
  #pragma unroll
  for(int i2=0;i2<16;++i2) b[i2]=0.f;
  for(int k=0;k<13;++k){
    if((m>>k)&1){
      #pragma unroll
      for(int i2=0;i2<16;++i2){
        float mx=-3.0e38f;
        #pragma unroll
        for(int j=0;j<16;++j) mx=fmaxf(mx, S[k*256+i2*16+j]+b[j]);
        float s=0.f;
        #pragma unroll
        for(int j=0;j<16;++j) s+=__expf(S[k*256+i2*16+j]+b[j]-mx);
        w[i2]=mx+__logf(s);
      }
      #pragma unroll
      for(int i2=0;i2<16;++i2) b[i2]=w[i2];
    }
  }
  #pragma unroll
  for(int i2=0;i2<16;++i2) wsf[F_BETA+(size_t)n*16+i2]=b[i2];
}

__global__ __launch_bounds__(256) void k_cat(const float* tl, float* wsf, float* out){
  __shared__ float Ts[256]; __shared__ float al[1024]; __shared__ float be[1040];
  int tid=threadIdx.x;
  Ts[tid]=tl[tid];
  float logZ = wsf[F_SC+0];
  int n0=blockIdx.x*64;
  for(int q=tid;q<1024;q+=256){ int n=n0+(q>>4); al[q] = (n<NN)? wsf[F_ALPHA+(size_t)n*16+(q&15)] : 0.f; }
  for(int q=tid;q<1040;q+=256){ int n=n0+(q>>4); be[q] = (n<NN)? wsf[F_BETA +(size_t)n*16+(q&15)] : 0.f; }
  __syncthreads();
  for(int q=tid;q<1024;q+=256){ int n=n0+(q>>4);
    if(n<NN) out[O_CAT+(size_t)n*16+(q&15)] = __expf(al[q]+be[q]-logZ); }
  int i=tid>>4, j=tid&15;
  float acc=0.f;
  #pragma unroll 4
  for(int nn=0;nn<64;++nn){
    int n=n0+nn;
    if(n<NN-1) acc += __expf(al[nn*16+i]+Ts[i*16+j]+be[(nn+1)*16+j]-logZ);
  }
  wsf[F_EZ + blockIdx.x*256 + tid]=acc;
}

// ---------------- F1: chunk aggregates -> XB0 ----------------
__global__ __launch_bounds__(256,4) void kf_agg(const float* rJ, const float* rh,
                                                float* wsf, double* wsd, float* out,
                                                unsigned long long xb0){
  __shared__ __align__(16) float C[2148];
  __shared__ __align__(16) float W[1152], Li[1152], BA[1152], BB[1152], CLAMA[1152], CATA[1152];
  __shared__ float rdg[32], Lu[32], uv[32], ev[32], catb[32];
  int tid=threadIdx.x; int i=blockIdx.x;
  if(i==0 && tid==0) wsf[F_SCAN+FLGOFF]=0.f;   // slot 0 = affine pad (flag 0)
  t36_rows(CLAMA, wsf+F_LAMA, tid);
  for(int q=tid;q<528;q+=256){ int r,c; tri_rc(q,r,c);
    float v=wsf[F_ATLAMA+r*32+c]+((r==c)?1e-6f:0.f); CATA[r*36+c]=v; CATA[c*36+r]=v; }
  if(tid<32) catb[tid]=wsf[F_ATLAMB+tid];
  if(i==0) unary_f(C, wsf, wsd, tid);
  else     leaf_f(C, 8*i, rJ, rh, wsf, wsd, tid);
  for(int e=1;e<8;++e)
    adv_leaf_f<0>(C, 8*i+e, rJ, rh, wsf, wsd, CLAMA, CATA, catb,
                  W,Li,BA,BB, rdg,Lu,uv,ev, (float*)0, (float*)0, (const float*)0, tid);
  __syncthreads();
  st_x(out, xb0, i, C, tid);
}

// ---------------- F2: Kogge-Stone level ----------------
__global__ __launch_bounds__(256,4) void kf_ks(float* out, int d,
                                               unsigned long long sb, unsigned long long db){
  __shared__ __align__(16) float C[2148], Y[2148];
  __shared__ __align__(16) float W[1152], Li[1152], BA[1152], BB[1152];
  __shared__ float rdg[32], Ls[32];
  int tid=threadIdx.x; int i=blockIdx.x;
  if(i<d){
    const float4* s=(const float4*)(out+sb+(size_t)i*XSLOT);
    float4* dd=(float4*)(out+db+(size_t)i*XSLOT);
    #pragma unroll 3
    for(int q=tid;q<537;q+=256) dd[q]=s[q];
    return;
  }
  ld_x(C, out, sb, i-d, tid);
  ld_x(Y, out, sb, i,   tid);
  comb_f(C, Y, W,Li,BA,BB, rdg,Ls, tid);
  st_x(out, db, i, C, tid);
}

// ---------------- F3: propagate + fused point ----------------
__global__ __launch_bounds__(256,4) void kf_prop(const float* rJ, const float* rh,
                                                 float* wsf, double* wsd, float* out,
                                                 unsigned long long xb0){
  __shared__ __align__(16) float C[2148];
  __shared__ __align__(16) float W[1152], Li[1152], BA[1152], BB[1152], CLAMA[1152], CATA[1152];
  __shared__ float rdg[32], Lu[32], uv[32], ev[32], catb[32], gv[32];
  int tid=threadIdx.x; int i=blockIdx.x;
  if(i>0) ld_x(C, out, xb0, i-1, tid);    // exclusive prefix of chunk i
  t36_rows(CLAMA, wsf+F_LAMA, tid);
  for(int q=tid;q<528;q+=256){ int r,c; tri_rc(q,r,c);
    float v=wsf[F_ATLAMA+r*32+c]+((r==c)?1e-6f:0.f); CATA[r*36+c]=v; CATA[c*36+r]=v; }
  if(tid<32) catb[tid]=wsf[F_ATLAMB+tid];
  for(int e=0;e<8;++e){
    int j=8*i+e;
    if(j==0){
      unary_f(C, wsf, wsd, tid);
    } else {
      adv_leaf_f<1>(C, j, rJ, rh, wsf, wsd, CLAMA, CATA, catb,
                    W,Li,BA,BB, rdg,Lu,uv,ev,
                    wsf + F_SCAN + (size_t)j*SSTR,
                    out + O_CROSS + (size_t)(j-1)*1024,
                    out + O_Z, tid);
    }
  }
  if(i==1023) final_f(C, W,Li,BB, rdg,Lu,uv,ev,gv, wsf, wsd, out, tid);
}

// ---------------- A1: affine chunk aggregates -> XB0 ----------------
__global__ __launch_bounds__(256,4) void ka_agg(float* wsf, float* out, unsigned long long xb0){
  __shared__ __align__(16) float C[2148], Y[2148];
  __shared__ __align__(16) float B1[1152], B2[1152], B3[1152], B4[1152];
  __shared__ float vcz[32], vcm[32];
  int tid=threadIdx.x; int i=blockIdx.x;
  ld_slot(C, wsf + F_SCAN + (size_t)(NN-8*i)*SSTR, tid);
  for(int e=1;e<8;++e){
    int j=8*i+e; int s=(j<NN)? (NN-j) : 0;
    ld_slot(Y, wsf + F_SCAN + (size_t)s*SSTR, tid);
    comb_a(C, Y, B1,B2,B3,B4, vcz,vcm, tid);
  }
  __syncthreads();
  st_x(out, xb0, i, C, tid);
}

// ---------------- A2: Kogge-Stone level (last level publishes to O_CROSS tails) ----------------
template<int PUB>
__global__ __launch_bounds__(256,4) void ka_ks(float* out, int d,
                                               unsigned long long sb, unsigned long long db){
  __shared__ __align__(16) float C[2148], Y[2148];
  __shared__ __align__(16) float B1[1152], B2[1152], B3[1152], B4[1152];
  __shared__ float vcz[32], vcm[32];
  int tid=threadIdx.x; int i=blockIdx.x;
  if(i<d){
    const float4* s=(const float4*)(out+sb+(size_t)i*XSLOT);
    float4* dd=(float4*)(out+db+(size_t)i*XSLOT);
    #pragma unroll 3
    for(int q=tid;q<537;q+=256){ float4 v=s[q]; dd[q]=v; if(PUB) ((float4*)C)[q]=v; }
    if(PUB){
      if(i<1023) st_pref(out+O_CROSS, i+1, C, tid);     // pseudo-slot i+1 = exclusive prefix
      if(i==0 && tid==0) out[O_CROSS + 4*1024 + 560 + 288 + 2] = 0.f;  // pseudo-slot 0 flag=0
    }
    return;
  }
  ld_x(C, out, sb, i-d, tid);
  ld_x(Y, out, sb, i,   tid);
  comb_a(C, Y, B1,B2,B3,B4, vcz,vcm, tid);
  st_x(out, db, i, C, tid);
  if(PUB && i<1023) st_pref(out+O_CROSS, i+1, C, tid);
}

// ---------------- A3: propagate + fused apply ----------------
__global__ __launch_bounds__(256,4) void ka_prop(float* wsf, float* out){
  __shared__ __align__(16) float C[2148], Y[2148];
  __shared__ __align__(16) float B1[1152], B2[1152], B3[1152], B4[1152];
  __shared__ float vcz[32], vcm[32], mlv[32], xtv[32], mv[32];
  int tid=threadIdx.x; int i=blockIdx.x;
  ld_pref(C, out + O_CROSS, SAGG0+i, tid);
  if(tid<32){ mlv[tid]=wsf[F_MLAST+tid]; xtv[tid]=wsf[F_XT+tid]; }
  __syncthreads();
  for(int e=0;e<8;++e){
    int j=8*i+e;
    if(j>0){
      int t=NN-j;
      t36_rows(B1, C+BG, tid);
      t36_rows(B4, wsf+F_COVT, tid);
      __syncthreads();
      if(tid<32){
        float am=0.f, az=0.f;
        #pragma unroll
        for(int m=0;m<32;++m){ float g=B1[tid*36+m]; am=fmaf(g,mlv[m],am); az=fmaf(g,xtv[m],az); }
        mv[tid]=am+C[BCM+tid];
        out[O_EX+(size_t)t*32+tid]=mv[tid];
        out[O_Z +(size_t)t*32+tid]=az+C[BCZ+tid];
      }
      {   // B2[r][c] = dot(B1[r], B4[c])
        int c=tid&31, rb=tid>>5; float res[4];
        dot36_x4(B1, rb, B4, c, res);
        #pragma unroll
        for(int k=0;k<4;++k) B2[(rb+8*k)*36+c]=res[k];
      }
      __syncthreads();
      #pragma unroll 3
      for(int q=tid;q<528;q+=256){
        int r,c; tri_rc(q,r,c);
        float e2 = dot36(B2,r,B1,c) + C[BP+q] + mv[r]*mv[c];
        out[O_EXXT+(size_t)t*1024 + r*32+c]=e2;
        if(r!=c) out[O_EXXT+(size_t)t*1024 + c*32+r]=e2;
      }
    }
    int s=(j<NN)? (NN-j) : 0;
    ld_slot(Y, wsf + F_SCAN + (size_t)s*SSTR, tid);
    comb_a(C, Y, B1,B2,B3,B4, vcz,vcm, tid);
  }
}

// ---------------- Cross_t ----------------
__global__ __launch_bounds__(256,6) void k_cross(float* wsf, float* out){
  __shared__ __align__(16) float PV36[1152], LA36[1152], E136[1152], GF36[1152];
  __shared__ float gv[32], m1[32];
  int tid=threadIdx.x;
  int t = blockIdx.x;
  float* outc = out + O_CROSS + (size_t)t*1024;
  t36_sym (PV36, outc, tid);
  t36_rows(LA36, wsf+F_LAMA, tid);
  t36_rows(E136, out+O_EXXT+(size_t)(t+1)*1024, tid);
  if(tid<32){ gv[tid]=outc[528+tid]; m1[tid]=out[O_EX+(size_t)(t+1)*32+tid]; }
  __syncthreads();
  {   // GF36[r][c] = dot(PV36[r], LA36[c])
    int c=tid&31, rb=tid>>5; float res[4];
    dot36_x4(PV36, rb, LA36, c, res);
    #pragma unroll
    for(int k=0;k<4;++k) GF36[(rb+8*k)*36+c]=res[k];
  }
  __syncthreads();
  {   // outc[i2*32+j] = dot(GF36[j], E136[i2]) + gv[j]*m1[i2] ; j=tid&31, i2=rb+8k
    int j=tid&31, rb=tid>>5; float res[4];
    dot36_x4(E136, rb, GF36, j, res);
    #pragma unroll
    for(int k=0;k<4;++k){
      int i2=rb+8*k;
      outc[i2*32+j] = res[k] + gv[j]*m1[i2];
    }
  }
}

// ---------------- big reduction over t ----------------
__global__ __launch_bounds__(256) void k_terms(const float* rJ, const float* rh,
    const float* plam, float* wsf, double* wsd, float* out){
  __shared__ float slam[1056], slamA[1056], sata[1056];
  __shared__ float slamb[32], satlb[32], cst[16], sw[16];
  __shared__ double sd[256];
  int tid=threadIdx.x; int i8=tid>>3, c4=(tid&7)*4;
  for(int p=0;p<4;p++){int cell=tid+(p<<8);int r=cell>>5,c=cell&31;
    slam[r*33+c]=wsf[F_LAM+cell]; slamA[r*33+c]=wsf[F_LAMA+cell]; sata[r*33+c]=wsf[F_ATLAMA+cell];}
  if(tid<32){slamb[tid]=wsf[F_LAMB+tid]; satlb[tid]=wsf[F_ATLAMB+tid];}
  if(tid<16) cst[tid] = -0.5f*wsf[F_BTLAMBK+tid] + 0.5f*wsf[F_LOGDETK+tid];
  __syncthreads();
  double dr=0.0, dt=0.0, dm=0.0;
  int t0=blockIdx.x*8;
  for(int tt=0;tt<8;++tt){
    int t=t0+tt;
    if(t<NN){ if(tid<16) sw[tid]=out[O_CAT+(size_t)t*16+tid]; }
    __syncthreads();
    size_t cb=(size_t)t*1024+((size_t)i8<<5)+c4;
    float4 exT=*(const float4*)(out+O_EXXT+cb);
    float4 rj =*(const float4*)(rJ+cb);
    dr += -0.5*(double)(rj.x*exT.x+rj.y*exT.y+rj.z*exT.z+rj.w*exT.w);
    if(tid<32) dr += (double)(rh[(size_t)t*32+tid]*out[O_EX+(size_t)t*32+tid]);
    if(t>=1){
      dt += -0.5*(double)(slam[i8*33+c4]*exT.x + slam[i8*33+c4+1]*exT.y
                        + slam[i8*33+c4+2]*exT.z + slam[i8*33+c4+3]*exT.w);
      if(tid<32) dt += (double)(slamb[tid]*out[O_EX+(size_t)t*32+tid]);
    }
    if(t<NN){
      float4 crT =*(const float4*)(out+O_CROSS+cb);
      float4 exT1=*(const float4*)(out+O_EXXT+cb+1024);
      dt += (double)(slamA[i8*33+c4]*crT.x + slamA[i8*33+c4+1]*crT.y
                   + slamA[i8*33+c4+2]*crT.z + slamA[i8*33+c4+3]*crT.w)
          -0.5*(double)(sata[i8*33+c4]*exT.x + sata[i8*33+c4+1]*exT.y
                      + sata[i8*33+c4+2]*exT.z + sata[i8*33+c4+3]*exT.w);
      if(tid<32) dt -= (double)(satlb[tid]*out[O_EX+(size_t)t*32+tid]);
      const float* pe1=(const float*)&exT1; const float* pcr=(const float*)&crT; const float* pe0=(const float*)&exT;
      #pragma unroll
      for(int q=0;q<4;q++){
        int cc=(i8<<5)+c4+q;
        float wl=0.f, wa=0.f, wt2=0.f;
        #pragma unroll
        for(int k2=0;k2<KK;k2++){ float wv=sw[k2];
          wl =fmaf(wv, plam[(size_t)k2*1024+cc], wl);
          wa =fmaf(wv, wsf[F_LAMAK+(size_t)k2*1024+cc], wa);
          wt2=fmaf(wv, wsf[F_ATLAMAK+(size_t)k2*1024+cc], wt2);}
        dm += (double)(-0.5f*wl*pe1[q] + wa*pcr[q] - 0.5f*wt2*pe0[q]);
      }
      if(tid<32){
        float wlb=0.f, wtb=0.f;
        #pragma unroll
        for(int k2=0;k2<KK;k2++){ wlb=fmaf(sw[k2], wsf[F_LAMBK+k2*32+tid], wlb);
                                  wtb=fmaf(sw[k2], wsf[F_ATLAMBK+k2*32+tid], wtb);}
        dm += (double)(wlb*out[O_EX+(size_t)(t+1)*32+tid] - wtb*out[O_EX+(size_t)t*32+tid]);
      }
      if(tid<16) dm += (double)(sw[tid]*cst[tid]);
    }
    __syncthreads();
  }
  double r1=blk_red(dr,sd,tid);
  double r2=blk_red(dt,sd,tid);
  double r3=blk_red(dm,sd,tid);
  if(tid==0){ wsd[WSD_PR+blockIdx.x]=r1; wsd[WSD_PT+blockIdx.x]=r2; wsd[WSD_PM+blockIdx.x]=r3; }
}

__global__ __launch_bounds__(256) void k_final(const float* il, const float* tl,
    const float* ilp, const float* tlp, const float* ptau, float* wsf, double* wsd, float* out){
  __shared__ double sd[256];
  int tid=threadIdx.x;
  double ez=0.0;
  for(int b=0;b<128;++b) ez += (double)wsf[F_EZ + b*256 + tid];
  double v = ez * (double)(tl[tid]-tlp[tid]);
  if(tid<16) v += (double)out[O_CAT+tid] * (double)(il[tid]-ilp[tid]);
  double hmmkl = blk_red(v, sd, tid) - (double)wsf[F_SC+0];
  double a=0,b2=0,c=0;
  for(int q=0;q<4;q++){int b3=tid+q*256; a+=wsd[WSD_PR+b3]; b2+=wsd[WSD_PT+b3]; c+=wsd[WSD_PM+b3];}
  double recog=blk_red(a,sd,tid), trns=blk_red(b2,sd,tid), mixt=blk_red(c,sd,tid);
  double ia=0, ib=0, va=0, vb=0;
  for(int p=0;p<4;p++){int cell=tid+(p<<8);
    float e0=out[O_EXXT+cell];
    ia += (double)(wsf[F_TAU+cell]*e0);
    ib += (double)(ptau[cell]*e0);
  }
  if(tid<32){ float ex0=out[O_EX+tid];
    va=(double)(ex0*wsf[F_TAUMU+tid]); vb=(double)(ex0*wsf[F_TPM+tid]); }
  double s_ia=blk_red(ia,sd,tid), s_ib=blk_red(ib,sd,tid);
  double s_va=blk_red(va,sd,tid), s_vb=blk_red(vb,sd,tid);
  if(tid==0){
    double init_term = -0.5*s_ia + s_va + wsd[WSD_LOGC0];
    double mix_init  = -0.5*s_ib + s_vb + wsd[WSD_MIXC];
    double trans_term = trns + (double)NN*(-0.5*wsd[WSD_BTLAMB] + 0.5*wsd[WSD_LDLAM] - 0.5*Dd*LOG2PI_);
    double mix_trans  = mixt - 0.5*(double)NN*(double)Dd*LOG2PI_;
    double lds_kl = (init_term+trans_term) + recog - wsd[WSD_LOGZQ] - (mix_init+mix_trans);
    out[O_KL] = (float)(lds_kl + hmmkl);
  }
}

// ---------------- launch ----------------
extern "C" void kernel_launch(void* const* d_in, const int* in_sizes, int n_in,
                              void* d_out, int out_size, void* d_ws, size_t ws_size,
                              hipStream_t stream){
  const float* rJ  =(const float*)d_in[0];
  const float* rh  =(const float*)d_in[1];
  const float* loc =(const float*)d_in[2];
  const float* Tp  =(const float*)d_in[3];
  const float* Lp  =(const float*)d_in[4];
  const float* X   =(const float*)d_in[5];
  const float* il  =(const float*)d_in[6];
  const float* tl  =(const float*)d_in[7];
  const float* plam=(const float*)d_in[8];
  const float* pX  =(const float*)d_in[9];
  const float* ptau=(const float*)d_in[10];
  const float* pmu =(const float*)d_in[11];
  const float* ilp =(const float*)d_in[12];
  const float* tlp =(const float*)d_in[13];
  const int*   seed=(const int*)d_in[14];
  float* out=(float*)d_out;
  double* wsd=(double*)d_ws;
  float* wsf=(float*)((char*)d_ws + 32768);

  const unsigned long long XB0 = (unsigned long long)O_EXXT;
  const unsigned long long XB1 = (unsigned long long)O_EXXT + 1024ull*XSLOT;

  k_setup<<<19,256,0,stream>>>(rJ,rh,loc,Tp,Lp,X,plam,pX,ptau,pmu,wsf,wsd);
  k_eps<<<1024,256,0,stream>>>(seed, out + O_Z);
  k_hmmpow<<<1,256,0,stream>>>(tl, wsf);
  k_hmmab<<<32,256,0,stream>>>(il, wsf);
  k_cat<<<128,256,0,stream>>>(tl, wsf, out);
  // filter scan: chunk aggregates -> Kogge-Stone inclusive -> propagate (fused point)
  kf_agg<<<1024,256,0,stream>>>(rJ, rh, wsf, wsd, out, XB0);
  for(int lv=0; lv<10; ++lv){
    unsigned long long sb = (lv&1)? XB1 : XB0;
    unsigned long long db = (lv&1)? XB0 : XB1;
    kf_ks<<<1024,256,0,stream>>>(out, 1<<lv, sb, db);
  }
  kf_prop<<<1024,256,0,stream>>>(rJ, rh, wsf, wsd, out, XB0);
  // affine scan (smoother + sampler): same structure, last KS level publishes prefixes
  ka_agg<<<1024,256,0,stream>>>(wsf, out, XB0);
  for(int lv=0; lv<9; ++lv){
    unsigned long long sb = (lv&1)? XB1 : XB0;
    unsigned long long db = (lv&1)? XB0 : XB1;
    ka_ks<0><<<1024,256,0,stream>>>(out, 1<<lv, sb, db);
  }
  ka_ks<1><<<1024,256,0,stream>>>(out, 512, XB1, XB0);
  ka_prop<<<1024,256,0,stream>>>(wsf, out);
  k_cross<<<NN,256,0,stream>>>(wsf, out);
  k_terms<<<1024,256,0,stream>>>(rJ, rh, plam, wsf, wsd, out);
  k_final<<<1,256,0,stream>>>(il, tl, ilp, tlp, ptau, wsf, wsd, out);
}